// Round 8
// baseline (16432.162 us; speedup 1.0000x reference)
//
#include <hip/hip_runtime.h>

// ---------------------------------------------------------------------------
// MoE forward: gating MLP + 8 dense experts + gate-weighted combine.
// All matmuls via mfma_f32_16x16x32_f16 (fp32 accum).
// r8: B-operand read DIRECTLY from global (k-major rows -> per-lane f16x8),
// register double-buffered. LDS holds A only (2 buffers): H kernel 64KB,
// OUT kernel 32KB. One barrier + one vmcnt(8) per K-tile; compiler-managed
// waits on B-reg loads transitively cover the older A-stage gload_lds.
// A-swizzle byte^=((row&7)<<4), inverse pre-applied on global source.
// ---------------------------------------------------------------------------

#define DI __device__ __forceinline__

typedef _Float16 f16;
typedef _Float16 f16x8 __attribute__((ext_vector_type(8)));
typedef float f32x4 __attribute__((ext_vector_type(4)));

constexpr int BSZ  = 8192;
constexpr int IND  = 1024;
constexpr int HID  = 4096;
constexpr int OUTD = 1024;
constexpr int NE   = 8;
constexpr int HGD  = 2048;

// ---------------- fp32 -> fp16 vectorized convert (8 elems/thread) ---------
__global__ __launch_bounds__(256) void conv_f32_f16_kernel(
    const float* __restrict__ in, f16* __restrict__ out)
{
    size_t i = ((size_t)blockIdx.x * 256 + threadIdx.x) * 8;
    const float4* p = (const float4*)(in + i);
    float4 a = p[0], b = p[1];
    f16x8 v = {(f16)a.x, (f16)a.y, (f16)a.z, (f16)a.w,
               (f16)b.x, (f16)b.y, (f16)b.z, (f16)b.w};
    *(f16x8*)(out + i) = v;
}

// ------------- transpose + convert: W[K][N] f32 -> Wt[N][K] f16 ------------
__global__ __launch_bounds__(256) void transpose_f32_f16_kernel(
    const float* __restrict__ W, f16* __restrict__ Wt, int K, int N)
{
    __shared__ float t[64][65];
    int n0 = blockIdx.x * 64, k0 = blockIdx.y * 64;
    int tx = threadIdx.x & 63, ty = threadIdx.x >> 6;
#pragma unroll
    for (int i = 0; i < 16; i++) {
        int k = i * 4 + ty;
        t[k][tx] = W[(size_t)(k0 + k) * N + n0 + tx];
    }
    __syncthreads();
#pragma unroll
    for (int i = 0; i < 16; i++) {
        int n = i * 4 + ty;
        Wt[(size_t)(n0 + n) * K + k0 + tx] = (f16)t[tx][n];
    }
}

// ---------------- async global->LDS (16B per lane, wave-uniform dest) ------
DI void gload_lds16(const void* g, void* l)
{
    typedef const __attribute__((address_space(1))) unsigned int as1_t;
    typedef __attribute__((address_space(3))) unsigned int as3_t;
    __builtin_amdgcn_global_load_lds(
        (as1_t*)(unsigned long long)(__SIZE_TYPE__)g,
        (as3_t*)(unsigned int)(__SIZE_TYPE__)l,
        16, 0, 0);
}

#define SB __builtin_amdgcn_sched_barrier(0);

// ---------------------------------------------------------------------------
// H/gating GEMM: BM=256, BN=256, BK=64, 8 waves 2Mx4N (wave tile 128x64).
// A in LDS (2 x 32KB, swizzled); B direct-global into reg dbuf.
// Per tile: vmcnt(8); barrier; rd mh0(8); [stA(t+1)x4; bl(t+1)x8]; rd mh1(8);
// lgkm(8); MFMA mh0(32); lgkm(0); MFMA mh1(32).
// ---------------------------------------------------------------------------
#define TILEH(BUF, BV, BVN, TT)                                                \
  {                                                                            \
    asm volatile("s_waitcnt vmcnt(8)");                                        \
    SB __builtin_amdgcn_s_barrier(); SB                                        \
    _Pragma("unroll") for (int f = 0; f < 4; f++)                              \
    _Pragma("unroll") for (int kc = 0; kc < 2; kc++)                           \
        av[f][kc] = *(const f16x8*)(sAc + (BUF) * 32768 + (offA[f] ^ (kc << 6))); \
    SB                                                                         \
    if ((TT) + 1 < NT) {                                                       \
        stA((BUF) ^ 1, 0, (TT) + 1); stA((BUF) ^ 1, 1, (TT) + 1);              \
        stA((BUF) ^ 1, 2, (TT) + 1); stA((BUF) ^ 1, 3, (TT) + 1);              \
        _Pragma("unroll") for (int f = 0; f < 4; f++)                          \
        _Pragma("unroll") for (int kc = 0; kc < 2; kc++)                       \
            BVN[f][kc] = *(const f16x8*)(pBf[f] + ((TT) + 1) * 64 + kc * 32);  \
    }                                                                          \
    SB                                                                         \
    _Pragma("unroll") for (int f = 0; f < 4; f++)                              \
    _Pragma("unroll") for (int kc = 0; kc < 2; kc++)                           \
        av[4 + f][kc] = *(const f16x8*)(sAc + (BUF) * 32768 + (offA[4 + f] ^ (kc << 6))); \
    asm volatile("s_waitcnt lgkmcnt(8)" ::: "memory");                         \
    SB                                                                         \
    __builtin_amdgcn_s_setprio(1);                                             \
    _Pragma("unroll") for (int f = 0; f < 4; f++)                              \
    _Pragma("unroll") for (int n = 0; n < 4; n++)                              \
    _Pragma("unroll") for (int kc = 0; kc < 2; kc++)                           \
        acc[f][n] = __builtin_amdgcn_mfma_f32_16x16x32_f16(                    \
            av[f][kc], BV[n][kc], acc[f][n], 0, 0, 0);                         \
    __builtin_amdgcn_s_setprio(0);                                             \
    asm volatile("s_waitcnt lgkmcnt(0)" ::: "memory");                         \
    SB                                                                         \
    __builtin_amdgcn_s_setprio(1);                                             \
    _Pragma("unroll") for (int f = 0; f < 4; f++)                              \
    _Pragma("unroll") for (int n = 0; n < 4; n++)                              \
    _Pragma("unroll") for (int kc = 0; kc < 2; kc++)                           \
        acc[4 + f][n] = __builtin_amdgcn_mfma_f32_16x16x32_f16(                \
            av[4 + f][kc], BV[n][kc], acc[4 + f][n], 0, 0, 0);                 \
    __builtin_amdgcn_s_setprio(0);                                             \
  }

template <bool RELU>
__global__ __launch_bounds__(512, 4) void gemmH_kernel(
    const f16* __restrict__ A, const f16* __restrict__ Bt,
    const float* __restrict__ bias, f16* __restrict__ Cptr,
    int M, int N, int K)
{
    constexpr int BM = 256, BN = 256, BK = 64;
    __shared__ __align__(16) f16 sA[2][BM * BK];   // 64KB total
    const char* sAc = (const char*)sA;

    const int tid = threadIdx.x, wid = tid >> 6, lane = tid & 63;
    const int wm = wid >> 2, wn = wid & 3;
    const int nwg = gridDim.x, bid = blockIdx.x;
    const int wg = (bid & 7) * (nwg >> 3) + (bid >> 3);
    const int gx = N / BN;
    const size_t bm = (size_t)(wg / gx) * BM;
    const size_t bn = (size_t)(wg % gx) * BN;

    f32x4 acc[8][4] = {};

    // A stage source (inverse swizzle, rule #21)
    const int rho  = tid >> 3;
    const int slot = (((tid & 7) << 4) ^ (((tid >> 3) & 7) << 4));
    const f16* pA = A + (bm + rho) * (size_t)K + (slot >> 1);

    auto stA = [&](int b, int q, int T) {
        gload_lds16(pA + ((size_t)q * 64) * K + (size_t)T * BK,
                    (char*)sAc + b * 32768 + q * 8192 + wid * 1024);
    };

    int offA[8];
#pragma unroll
    for (int f = 0; f < 8; f++) {
        int r = wm * 128 + f * 16 + (lane & 15);
        offA[f] = r * 128 + ((((lane >> 4) << 4)) ^ ((r & 7) << 4));
    }
    // B direct-global per-fragment row pointers (k-contiguous 16B per lane)
    const f16* pBf[4];
#pragma unroll
    for (int f = 0; f < 4; f++) {
        int r = (int)bn + wn * 64 + f * 16 + (lane & 15);
        pBf[f] = Bt + (size_t)r * K + ((lane >> 4) << 3);
    }

    f16x8 av[8][2], bvA[4][2], bvB[4][2];
    const int NT = K / BK;   // even

    // prologue: stage A(0), load B(0) regs
    stA(0, 0, 0); stA(0, 1, 0); stA(0, 2, 0); stA(0, 3, 0);
#pragma unroll
    for (int f = 0; f < 4; f++)
#pragma unroll
        for (int kc = 0; kc < 2; kc++)
            bvA[f][kc] = *(const f16x8*)(pBf[f] + kc * 32);

    for (int t = 0; t < NT; t += 2) {
        TILEH(0, bvA, bvB, t)
        TILEH(1, bvB, bvA, t + 1)
    }

    // epilogue: C/D layout col=lane&15, row=(lane>>4)*4+reg
    const size_t row0 = bm + (size_t)wm * 128;
    const int col0 = (int)bn + wn * 64;
    const int c0 = lane & 15, r0 = (lane >> 4) * 4;
#pragma unroll
    for (int fm = 0; fm < 8; fm++)
#pragma unroll
        for (int r = 0; r < 4; r++) {
            const size_t row = row0 + fm * 16 + r0 + r;
#pragma unroll
            for (int n = 0; n < 4; n++) {
                const size_t col = (size_t)col0 + n * 16 + c0;
                float v = acc[fm][n][r] + bias[col];
                if constexpr (RELU) v = fmaxf(v, 0.0f);
                Cptr[row * (size_t)N + col] = (f16)v;
            }
        }
}

// ---------------------------------------------------------------------------
// OUT GEMM: BM=128, BN=128, BK=64, 4 waves 2Mx2N (wave tile 64x64).
// A in LDS (2 x 16KB); B direct-global reg dbuf. Grid 512. Same tile sync.
// ---------------------------------------------------------------------------
#define TILEO(BUF, BV, BVN, TT)                                                \
  {                                                                            \
    asm volatile("s_waitcnt vmcnt(8)");                                        \
    SB __builtin_amdgcn_s_barrier(); SB                                        \
    _Pragma("unroll") for (int f = 0; f < 4; f++)                              \
    _Pragma("unroll") for (int kc = 0; kc < 2; kc++)                           \
        av[f][kc] = *(const f16x8*)(sAc + (BUF) * 16384 + (offA[f] ^ (kc << 6))); \
    SB                                                                         \
    if ((TT) + 1 < NT) {                                                       \
        stA((BUF) ^ 1, 0, (TT) + 1); stA((BUF) ^ 1, 1, (TT) + 1);              \
        stA((BUF) ^ 1, 2, (TT) + 1); stA((BUF) ^ 1, 3, (TT) + 1);              \
        _Pragma("unroll") for (int f = 0; f < 4; f++)                          \
        _Pragma("unroll") for (int kc = 0; kc < 2; kc++)                       \
            BVN[f][kc] = *(const f16x8*)(pBf[f] + ((TT) + 1) * 64 + kc * 32);  \
    }                                                                          \
    asm volatile("s_waitcnt lgkmcnt(0)" ::: "memory");                         \
    SB                                                                         \
    __builtin_amdgcn_s_setprio(1);                                             \
    _Pragma("unroll") for (int fa = 0; fa < 4; fa++)                           \
    _Pragma("unroll") for (int fb = 0; fb < 4; fb++)                           \
    _Pragma("unroll") for (int kc = 0; kc < 2; kc++)                           \
        acc[fa][fb] = __builtin_amdgcn_mfma_f32_16x16x32_f16(                  \
            av[fa][kc], BV[fb][kc], acc[fa][fb], 0, 0, 0);                     \
    __builtin_amdgcn_s_setprio(0);                                             \
  }

template <bool ACCUM>
__global__ __launch_bounds__(256, 4) void gemmOB_kernel(
    const f16* __restrict__ A, const f16* __restrict__ Bt,
    const float* __restrict__ bias, const float* __restrict__ gate,
    float* __restrict__ Cptr, int M, int N, int K)
{
    constexpr int BM = 128, BN = 128, BK = 64;
    __shared__ __align__(16) f16 sA[2][BM * BK];   // 32KB total
    const char* sAc = (const char*)sA;

    const int tid = threadIdx.x, wid = tid >> 6, lane = tid & 63;
    const int wm = wid >> 1, wn = wid & 1;
    const int nwg = gridDim.x, bid = blockIdx.x;
    const int wg = (bid & 7) * (nwg >> 3) + (bid >> 3);
    const int gx = N / BN;
    const size_t bm = (size_t)(wg / gx) * BM;
    const size_t bn = (size_t)(wg % gx) * BN;

    f32x4 acc[4][4] = {};

    const int rho  = tid >> 3;     // 0..31 rows per 4KB call
    const int slot = (((tid & 7) << 4) ^ (((tid >> 3) & 7) << 4));
    const f16* pA = A + (bm + rho) * (size_t)K + (slot >> 1);

    auto stA = [&](int b, int q, int T) {
        gload_lds16(pA + ((size_t)q * 32) * K + (size_t)T * BK,
                    (char*)sAc + b * 16384 + q * 4096 + wid * 1024);
    };

    int offA[4];
#pragma unroll
    for (int f = 0; f < 4; f++) {
        int r = wm * 64 + f * 16 + (lane & 15);
        offA[f] = r * 128 + ((((lane >> 4) << 4)) ^ ((r & 7) << 4));
    }
    const f16* pBf[4];
#pragma unroll
    for (int f = 0; f < 4; f++) {
        int r = (int)bn + wn * 64 + f * 16 + (lane & 15);
        pBf[f] = Bt + (size_t)r * K + ((lane >> 4) << 3);
    }

    f16x8 av[4][2], bvA[4][2], bvB[4][2];
    const int NT = K / BK;   // 64

    stA(0, 0, 0); stA(0, 1, 0); stA(0, 2, 0); stA(0, 3, 0);
#pragma unroll
    for (int f = 0; f < 4; f++)
#pragma unroll
        for (int kc = 0; kc < 2; kc++)
            bvA[f][kc] = *(const f16x8*)(pBf[f] + kc * 32);

    for (int t = 0; t < NT; t += 2) {
        TILEO(0, bvA, bvB, t)
        TILEO(1, bvB, bvA, t + 1)
    }

    const size_t row0 = bm + (size_t)wm * 64;
    const int col0 = (int)bn + wn * 64;
    const int c0 = lane & 15, r0 = (lane >> 4) * 4;
#pragma unroll
    for (int fa = 0; fa < 4; fa++)
#pragma unroll
        for (int r = 0; r < 4; r++) {
            const size_t row = row0 + fa * 16 + r0 + r;
            const float g = gate[row * NE];
#pragma unroll
            for (int fb = 0; fb < 4; fb++) {
                const size_t col = (size_t)col0 + fb * 16 + c0;
                float v = (acc[fa][fb][r] + bias[col]) * g;
                float* p = Cptr + row * (size_t)N + col;
                *p = ACCUM ? (*p + v) : v;
            }
        }
}

// --------- gating head: logits = gh@gw2 + gb2, softmax -> gates fp32 -------
__global__ __launch_bounds__(256) void gate_softmax_kernel(
    const f16* __restrict__ gh, const float* __restrict__ gw2,
    const float* __restrict__ gb2, float* __restrict__ gates)
{
    const int row  = blockIdx.x * 4 + (threadIdx.x >> 6);
    const int lane = threadIdx.x & 63;
    const f16* r = gh + (size_t)row * HGD;
    float acc[NE] = {};
    for (int kb = lane * 8; kb < HGD; kb += 512) {
        f16x8 v = *(const f16x8*)(r + kb);
#pragma unroll
        for (int j = 0; j < 8; j++) {
            float h = (float)v[j];
            const float* w = gw2 + (size_t)(kb + j) * NE;
#pragma unroll
            for (int e = 0; e < NE; e++) acc[e] = fmaf(h, w[e], acc[e]);
        }
    }
#pragma unroll
    for (int off = 32; off > 0; off >>= 1)
#pragma unroll
        for (int e = 0; e < NE; e++) acc[e] += __shfl_down(acc[e], off, 64);
    if (lane == 0) {
        float l[NE], m = -1e30f;
#pragma unroll
        for (int e = 0; e < NE; e++) { l[e] = acc[e] + gb2[e]; m = fmaxf(m, l[e]); }
        float s = 0.f;
#pragma unroll
        for (int e = 0; e < NE; e++) { l[e] = expf(l[e] - m); s += l[e]; }
        float inv = 1.0f / s;
#pragma unroll
        for (int e = 0; e < NE; e++) gates[(size_t)row * NE + e] = l[e] * inv;
    }
}

// ---------------------------------------------------------------------------
extern "C" void kernel_launch(void* const* d_in, const int* in_sizes, int n_in,
                              void* d_out, int out_size, void* d_ws, size_t ws_size,
                              hipStream_t stream)
{
    const float* x   = (const float*)d_in[0];
    const float* gw1 = (const float*)d_in[1];
    const float* gb1 = (const float*)d_in[2];
    const float* gw2 = (const float*)d_in[3];
    const float* gb2 = (const float*)d_in[4];
    const float* ew1 = (const float*)d_in[5];
    const float* eb1 = (const float*)d_in[6];
    const float* ew2 = (const float*)d_in[7];
    const float* eb2 = (const float*)d_in[8];
    float* out = (float*)d_out;

    // ws layout: gates(256KB) | x16(16MB) | wbuf(8MB) | hbuf(64MB, gh aliases)
    char* ws = (char*)d_ws;
    float* gates = (float*)ws;
    f16* x16  = (f16*)(ws + (256 << 10));
    f16* wbuf = x16 + (size_t)BSZ * IND;
    f16* hbuf = wbuf + (size_t)HID * IND;
    f16* gh   = hbuf;  // alias: gh fully consumed before first expert GEMM

    // 1) x -> fp16
    conv_f32_f16_kernel<<<(BSZ * IND) / (256 * 8), 256, 0, stream>>>(x, x16);

    // 2) gating GEMM1: gh = relu(x @ gw1 + gb1)   [M=8192,N=2048,K=1024]
    transpose_f32_f16_kernel<<<dim3(HGD / 64, IND / 64), 256, 0, stream>>>(
        gw1, wbuf, IND, HGD);
    gemmH_kernel<true>
        <<<(HGD / 256) * (BSZ / 256), 512, 0, stream>>>(
            x16, wbuf, gb1, gh, BSZ, HGD, IND);

    // 3) gating head + softmax -> gates
    gate_softmax_kernel<<<BSZ / 4, 256, 0, stream>>>(gh, gw2, gb2, gates);

    // 4) experts
    for (int e = 0; e < NE; e++) {
        // h = relu(x @ ew1[e] + eb1[e])   [M=8192,N=4096,K=1024]
        transpose_f32_f16_kernel<<<dim3(HID / 64, IND / 64), 256, 0, stream>>>(
            ew1 + (size_t)e * IND * HID, wbuf, IND, HID);
        gemmH_kernel<true>
            <<<(HID / 256) * (BSZ / 256), 512, 0, stream>>>(
                x16, wbuf, eb1 + (size_t)e * HID, hbuf, BSZ, HID, IND);

        // out (+)= gates[:,e] * (h @ ew2[e] + eb2[e])   [M=8192,N=1024,K=4096]
        transpose_f32_f16_kernel<<<dim3(OUTD / 64, HID / 64), 256, 0, stream>>>(
            ew2 + (size_t)e * HID * OUTD, wbuf, HID, OUTD);
        if (e == 0)
            gemmOB_kernel<false>
                <<<(OUTD / 128) * (BSZ / 128), 256, 0, stream>>>(
                    hbuf, wbuf, eb2 + (size_t)e * OUTD, gates + e, out,
                    BSZ, OUTD, HID);
        else
            gemmOB_kernel<true>
                <<<(OUTD / 128) * (BSZ / 128), 256, 0, stream>>>(
                    hbuf, wbuf, eb2 + (size_t)e * OUTD, gates + e, out,
                    BSZ, OUTD, HID);
    }
}

// Round 9
// 1587.321 us; speedup vs baseline: 10.3521x; 10.3521x over previous
//
#include <hip/hip_runtime.h>

// ---------------------------------------------------------------------------
// MoE forward: gating MLP + 8 dense experts + gate-weighted combine.
// r9: r4-verified schedules, MFMA shape switched 16x16x32 -> 32x32x16
// (+15% ceiling, -18% matrix-pipe cycles, identical LDS image/traffic).
// gemm256: BM=256,BN=256,BK=64, 8 waves 2Mx4N; gemmO: BM=256,BN=128.
// LDS swizzle byte^=((row&7)<<4), inverse pre-applied on global source
// (rule #21). C/D layout (m74/m101): col=lane&31,
// row=(reg&3)+8*(reg>>2)+4*(lane>>5).
// ---------------------------------------------------------------------------

#define DI __device__ __forceinline__

typedef _Float16 f16;
typedef _Float16 f16x8 __attribute__((ext_vector_type(8)));
typedef float f32x16 __attribute__((ext_vector_type(16)));

constexpr int BSZ  = 8192;
constexpr int IND  = 1024;
constexpr int HID  = 4096;
constexpr int OUTD = 1024;
constexpr int NE   = 8;
constexpr int HGD  = 2048;

// ---------------- fp32 -> fp16 vectorized convert (8 elems/thread) ---------
__global__ __launch_bounds__(256) void conv_f32_f16_kernel(
    const float* __restrict__ in, f16* __restrict__ out)
{
    size_t i = ((size_t)blockIdx.x * 256 + threadIdx.x) * 8;
    const float4* p = (const float4*)(in + i);
    float4 a = p[0], b = p[1];
    f16x8 v = {(f16)a.x, (f16)a.y, (f16)a.z, (f16)a.w,
               (f16)b.x, (f16)b.y, (f16)b.z, (f16)b.w};
    *(f16x8*)(out + i) = v;
}

// ------------- transpose + convert: W[K][N] f32 -> Wt[N][K] f16 ------------
__global__ __launch_bounds__(256) void transpose_f32_f16_kernel(
    const float* __restrict__ W, f16* __restrict__ Wt, int K, int N)
{
    __shared__ float t[64][65];
    int n0 = blockIdx.x * 64, k0 = blockIdx.y * 64;
    int tx = threadIdx.x & 63, ty = threadIdx.x >> 6;
#pragma unroll
    for (int i = 0; i < 16; i++) {
        int k = i * 4 + ty;
        t[k][tx] = W[(size_t)(k0 + k) * N + n0 + tx];
    }
    __syncthreads();
#pragma unroll
    for (int i = 0; i < 16; i++) {
        int n = i * 4 + ty;
        Wt[(size_t)(n0 + n) * K + k0 + tx] = (f16)t[tx][n];
    }
}

// ---------------- async global->LDS (16B per lane, wave-uniform dest) ------
DI void gload_lds16(const void* g, void* l)
{
    typedef const __attribute__((address_space(1))) unsigned int as1_t;
    typedef __attribute__((address_space(3))) unsigned int as3_t;
    __builtin_amdgcn_global_load_lds(
        (as1_t*)(unsigned long long)(__SIZE_TYPE__)g,
        (as3_t*)(unsigned int)(__SIZE_TYPE__)l,
        16, 0, 0);
}

// sync building blocks (rule #18: sched_barrier after lgkmcnt before MFMA)
#define SYNC_HEAD                                                              \
    __builtin_amdgcn_sched_barrier(0);                                         \
    __builtin_amdgcn_s_barrier();                                              \
    asm volatile("s_waitcnt lgkmcnt(0)" ::: "memory");                         \
    __builtin_amdgcn_sched_barrier(0);
#define SYNC_HEAD_T8                                                           \
    __builtin_amdgcn_sched_barrier(0);                                         \
    asm volatile("s_waitcnt lgkmcnt(8)");                                      \
    __builtin_amdgcn_s_barrier();                                              \
    asm volatile("s_waitcnt lgkmcnt(0)" ::: "memory");                         \
    __builtin_amdgcn_sched_barrier(0);
#define SYNC_TAIL                                                              \
    __builtin_amdgcn_sched_barrier(0);                                         \
    __builtin_amdgcn_s_barrier();                                              \
    asm volatile("" ::: "memory");

// ---------------------------------------------------------------------------
// gemm256: BM=256, BN=256, BK=64, 8 waves 2Mx4N (wave tile 128x64).
// 32x32x16 frags: A-frags 4 (2 per mh), B-frags 2 (nh0/nh1), 4 k-steps.
// Phase reads identical to r4 (12/4/8/0 b128); same stage/vmcnt schedule.
// ---------------------------------------------------------------------------
template <bool RELU>
__global__ __launch_bounds__(512, 2) void gemm256_kernel(
    const f16* __restrict__ A, const f16* __restrict__ Bt,
    const float* __restrict__ bias, f16* __restrict__ Cptr,
    int M, int N, int K)
{
    constexpr int BM = 256, BN = 256, BK = 64;
    constexpr int AT = BM * BK * 2, BT = BN * BK * 2;   // 32768 each
    __shared__ __align__(16) f16 sA[2][BM * BK];
    __shared__ __align__(16) f16 sB[2][BN * BK];
    const char* sAc = (const char*)sA;
    const char* sBc = (const char*)sB;

    const int tid = threadIdx.x, wid = tid >> 6, lane = tid & 63;
    const int wm = wid >> 2, wn = wid & 3;
    const int nwg = gridDim.x, bid = blockIdx.x;
    const int wg = (bid & 7) * (nwg >> 3) + (bid >> 3);
    const int gx = N / BN;
    const size_t bm = (size_t)(wg / gx) * BM;
    const size_t bn = (size_t)(wg % gx) * BN;

    f32x16 acc[4][2] = {};   // [m-frag 32rows][n-frag 32cols]

    // stage source (inverse swizzle on global source, rule #21)
    const int rho  = tid >> 3;
    const int slot = (((tid & 7) << 4) ^ (((tid >> 3) & 7) << 4));
    const f16* pA = A  + (bm + rho) * (size_t)K + (slot >> 1);
    const f16* pB = Bt + (bn + rho) * (size_t)K + (slot >> 1);

    auto stA = [&](int b, int q, int T) {
        gload_lds16(pA + ((size_t)q * 64) * K + (size_t)T * BK,
                    (char*)sAc + b * AT + q * 8192 + wid * 1024);
    };
    auto stB = [&](int b, int q, int T) {
        gload_lds16(pB + ((size_t)q * 64) * K + (size_t)T * BK,
                    (char*)sBc + b * BT + q * 8192 + wid * 1024);
    };

    // fragment base offsets (swizzled); k-step toggles via ^ (ks<<5)
    // (bits 5-6 of ks<<5 disjoint from the (lane>>5)<<4 bit-4 part)
    int offA[4], offB0v[2];
#pragma unroll
    for (int f = 0; f < 4; f++) {
        int r = wm * 128 + f * 32 + (lane & 31);
        offA[f] = r * 128 + ((((lane >> 5) << 4)) ^ ((r & 7) << 4));
    }
#pragma unroll
    for (int f = 0; f < 2; f++) {
        int r = wn * 64 + f * 32 + (lane & 31);
        offB0v[f] = r * 128 + ((((lane >> 5) << 4)) ^ ((r & 7) << 4));
    }

    f16x8 av[2][4], bv0[4], bv1[4];

#define LDAQ(B, MH)                                                            \
    _Pragma("unroll") for (int f = 0; f < 2; f++)                              \
    _Pragma("unroll") for (int ks = 0; ks < 4; ks++)                           \
        av[f][ks] = *(const f16x8*)(sAc + (B) * AT + (offA[(MH)*2+f] ^ (ks << 5)));
#define LDBH(B, NH, BV)                                                        \
    _Pragma("unroll") for (int ks = 0; ks < 4; ks++)                           \
        BV[ks] = *(const f16x8*)(sBc + (B) * BT + (offB0v[NH] ^ (ks << 5)));
#define QUAD(MH, NH, BV)                                                       \
    __builtin_amdgcn_s_setprio(1);                                             \
    _Pragma("unroll") for (int f = 0; f < 2; f++)                              \
    _Pragma("unroll") for (int ks = 0; ks < 4; ks++)                           \
        acc[(MH)*2+f][NH] = __builtin_amdgcn_mfma_f32_32x32x16_f16(            \
            av[f][ks], BV[ks], acc[(MH)*2+f][NH], 0, 0, 0);                    \
    __builtin_amdgcn_s_setprio(0);

    const int NT = K / BK, NI = NT / 2;

    stA(0,0,0); stA(0,2,0); stB(0,0,0); stB(0,1,0); stB(0,2,0); stB(0,3,0);
    stA(0,1,0); stA(0,3,0);
    stA(1,0,1); stA(1,2,1); stB(1,0,1); stB(1,1,1); stB(1,2,1); stB(1,3,1);
    asm volatile("s_waitcnt vmcnt(6)");
    __builtin_amdgcn_s_barrier();
    asm volatile("" ::: "memory");

    for (int i = 0; i < NI - 1; ++i) {
        const int t = 2 * i;
        LDAQ(0, 0) LDBH(0, 0, bv0)
        stA(1, 1, t + 1); stA(1, 3, t + 1);
        SYNC_HEAD_T8
        QUAD(0, 0, bv0)
        SYNC_TAIL
        LDBH(0, 1, bv1)
        stA(0, 0, t + 2); stA(0, 2, t + 2);
        SYNC_HEAD
        QUAD(0, 1, bv1)
        SYNC_TAIL
        LDAQ(0, 1)
        stB(0, 0, t + 2); stB(0, 1, t + 2);
        SYNC_HEAD
        QUAD(1, 1, bv1)
        SYNC_TAIL
        stB(0, 2, t + 2); stB(0, 3, t + 2);
        SYNC_HEAD
        QUAD(1, 0, bv0)
        asm volatile("s_waitcnt vmcnt(6)");
        SYNC_TAIL
        LDAQ(1, 0) LDBH(1, 0, bv0)
        stA(0, 1, t + 2); stA(0, 3, t + 2);
        SYNC_HEAD_T8
        QUAD(0, 0, bv0)
        SYNC_TAIL
        LDBH(1, 1, bv1)
        stA(1, 0, t + 3); stA(1, 2, t + 3);
        SYNC_HEAD
        QUAD(0, 1, bv1)
        SYNC_TAIL
        LDAQ(1, 1)
        stB(1, 0, t + 3); stB(1, 1, t + 3);
        SYNC_HEAD
        QUAD(1, 1, bv1)
        SYNC_TAIL
        stB(1, 2, t + 3); stB(1, 3, t + 3);
        SYNC_HEAD
        QUAD(1, 0, bv0)
        asm volatile("s_waitcnt vmcnt(6)");
        SYNC_TAIL
    }
    {   // final iteration (tiles NT-2, NT-1)
        LDAQ(0, 0) LDBH(0, 0, bv0)
        stA(1, 1, NT - 1); stA(1, 3, NT - 1);
        SYNC_HEAD_T8
        QUAD(0, 0, bv0)
        SYNC_TAIL
        LDBH(0, 1, bv1)
        SYNC_HEAD
        QUAD(0, 1, bv1)
        SYNC_TAIL
        LDAQ(0, 1)
        SYNC_HEAD
        QUAD(1, 1, bv1)
        SYNC_TAIL
        SYNC_HEAD
        QUAD(1, 0, bv0)
        asm volatile("s_waitcnt vmcnt(0)");
        SYNC_TAIL
        LDAQ(1, 0) LDBH(1, 0, bv0)
        SYNC_HEAD
        QUAD(0, 0, bv0)
        SYNC_TAIL
        LDBH(1, 1, bv1)
        SYNC_HEAD
        QUAD(0, 1, bv1)
        SYNC_TAIL
        LDAQ(1, 1)
        SYNC_HEAD
        QUAD(1, 1, bv1)
        SYNC_TAIL
        SYNC_HEAD
        QUAD(1, 0, bv0)
        SYNC_TAIL
    }
#undef LDAQ
#undef LDBH
#undef QUAD

    // epilogue: 32x32 C/D layout col=lane&31, row=(reg&3)+8*(reg>>2)+4*(lane>>5)
    const size_t row0 = bm + (size_t)wm * 128;
    const int col0 = (int)bn + wn * 64;
    const int c0 = lane & 31, rhi = 4 * (lane >> 5);
#pragma unroll
    for (int fm = 0; fm < 4; fm++)
#pragma unroll
        for (int reg = 0; reg < 16; reg++) {
            const size_t row = row0 + fm * 32 + (reg & 3) + 8 * (reg >> 2) + rhi;
#pragma unroll
            for (int fn = 0; fn < 2; fn++) {
                const size_t col = (size_t)col0 + fn * 32 + c0;
                float v = acc[fm][fn][reg] + bias[col];
                if constexpr (RELU) v = fmaxf(v, 0.0f);
                Cptr[row * (size_t)N + col] = (f16)v;
            }
        }
}

// ---------------------------------------------------------------------------
// gemmO: BM=256, BN=128, BK=64, 8 waves 2Mx4N (wave tile 128x32).
// 32x32x16: A-frags 4, B-frag 1 (4 k-steps). Phases (mh,kh), 4 MFMA each;
// reads 4 A per phase + 4 B at P1. r4 stage/vmcnt schedule verbatim.
// ---------------------------------------------------------------------------
template <bool ACCUM>
__global__ __launch_bounds__(512, 2) void gemmO_kernel(
    const f16* __restrict__ A, const f16* __restrict__ Bt,
    const float* __restrict__ bias, const float* __restrict__ gate,
    float* __restrict__ Cptr, int M, int N, int K)
{
    constexpr int BM = 256, BN = 128, BK = 64;
    constexpr int AT = BM * BK * 2, BT = BN * BK * 2;   // 32768 / 16384
    __shared__ __align__(16) f16 sA[2][BM * BK];
    __shared__ __align__(16) f16 sB[2][BN * BK];
    const char* sAc = (const char*)sA;
    const char* sBc = (const char*)sB;

    const int tid = threadIdx.x, wid = tid >> 6, lane = tid & 63;
    const int wm = wid >> 2, wn = wid & 3;
    const int nwg = gridDim.x, bid = blockIdx.x;
    const int wg = (bid & 7) * (nwg >> 3) + (bid >> 3);
    const int gx = N / BN;
    const size_t bm = (size_t)(wg / gx) * BM;
    const size_t bn = (size_t)(wg % gx) * BN;

    f32x16 acc[4] = {};   // 4 m-frags x 1 n-frag

    const int rho  = tid >> 3;
    const int slot = (((tid & 7) << 4) ^ (((tid >> 3) & 7) << 4));
    const f16* pA = A  + (bm + rho) * (size_t)K + (slot >> 1);
    const f16* pB = Bt + (bn + rho) * (size_t)K + (slot >> 1);

    auto stA = [&](int b, int q, int T) {
        gload_lds16(pA + ((size_t)q * 64) * K + (size_t)T * BK,
                    (char*)sAc + b * AT + q * 8192 + wid * 1024);
    };
    auto stB = [&](int b, int q, int T) {
        gload_lds16(pB + ((size_t)q * 64) * K + (size_t)T * BK,
                    (char*)sBc + b * BT + q * 8192 + wid * 1024);
    };

    int offA[4], offB0;
#pragma unroll
    for (int f = 0; f < 4; f++) {
        int r = wm * 128 + f * 32 + (lane & 31);
        offA[f] = r * 128 + ((((lane >> 5) << 4)) ^ ((r & 7) << 4));
    }
    {
        int r = wn * 32 + (lane & 31);
        offB0 = r * 128 + ((((lane >> 5) << 4)) ^ ((r & 7) << 4));
    }

    f16x8 av[2][2], bv[4];

#define LDA2(B, MH, KH)                                                        \
    _Pragma("unroll") for (int f = 0; f < 2; f++)                              \
    _Pragma("unroll") for (int j = 0; j < 2; j++)                              \
        av[f][j] = *(const f16x8*)(sAc + (B) * AT +                            \
                                   (offA[(MH)*2+f] ^ (((KH)*2+j) << 5)));
#define LDBA(B)                                                                \
    _Pragma("unroll") for (int ks = 0; ks < 4; ks++)                           \
        bv[ks] = *(const f16x8*)(sBc + (B) * BT + (offB0 ^ (ks << 5)));
#define OCT(MH, KH)                                                            \
    __builtin_amdgcn_s_setprio(1);                                             \
    _Pragma("unroll") for (int f = 0; f < 2; f++)                              \
    _Pragma("unroll") for (int j = 0; j < 2; j++)                              \
        acc[(MH)*2+f] = __builtin_amdgcn_mfma_f32_32x32x16_f16(                \
            av[f][j], bv[(KH)*2+j], acc[(MH)*2+f], 0, 0, 0);                   \
    __builtin_amdgcn_s_setprio(0);

    const int NT = K / BK, NI = NT / 2;

    stA(0,0,0); stA(0,2,0); stB(0,0,0); stB(0,1,0); stA(0,1,0); stA(0,3,0);
    stA(1,0,1); stA(1,2,1); stB(1,0,1); stB(1,1,1);
    asm volatile("s_waitcnt vmcnt(4)");
    __builtin_amdgcn_s_barrier();
    asm volatile("" ::: "memory");

    for (int i = 0; i < NI - 1; ++i) {
        const int t = 2 * i;
        LDA2(0, 0, 0) LDBA(0)
        stA(1, 1, t + 1); stA(1, 3, t + 1);
        SYNC_HEAD
        OCT(0, 0)
        SYNC_TAIL
        LDA2(0, 0, 1)
        SYNC_HEAD
        OCT(0, 1)
        SYNC_TAIL
        LDA2(0, 1, 0)
        stA(0, 0, t + 2); stA(0, 2, t + 2);
        SYNC_HEAD
        OCT(1, 0)
        SYNC_TAIL
        LDA2(0, 1, 1)
        stB(0, 0, t + 2); stB(0, 1, t + 2);
        SYNC_HEAD
        OCT(1, 1)
        asm volatile("s_waitcnt vmcnt(4)");
        SYNC_TAIL
        LDA2(1, 0, 0) LDBA(1)
        stA(0, 1, t + 2); stA(0, 3, t + 2);
        SYNC_HEAD
        OCT(0, 0)
        SYNC_TAIL
        LDA2(1, 0, 1)
        SYNC_HEAD
        OCT(0, 1)
        SYNC_TAIL
        LDA2(1, 1, 0)
        stA(1, 0, t + 3); stA(1, 2, t + 3);
        SYNC_HEAD
        OCT(1, 0)
        SYNC_TAIL
        LDA2(1, 1, 1)
        stB(1, 0, t + 3); stB(1, 1, t + 3);
        SYNC_HEAD
        OCT(1, 1)
        asm volatile("s_waitcnt vmcnt(4)");
        SYNC_TAIL
    }
    {   // final iteration
        LDA2(0, 0, 0) LDBA(0)
        stA(1, 1, NT - 1); stA(1, 3, NT - 1);
        SYNC_HEAD
        OCT(0, 0)
        SYNC_TAIL
        LDA2(0, 0, 1)
        SYNC_HEAD
        OCT(0, 1)
        SYNC_TAIL
        LDA2(0, 1, 0)
        SYNC_HEAD
        OCT(1, 0)
        SYNC_TAIL
        LDA2(0, 1, 1)
        SYNC_HEAD
        OCT(1, 1)
        asm volatile("s_waitcnt vmcnt(0)");
        SYNC_TAIL
        LDA2(1, 0, 0) LDBA(1)
        SYNC_HEAD
        OCT(0, 0)
        SYNC_TAIL
        LDA2(1, 0, 1)
        SYNC_HEAD
        OCT(0, 1)
        SYNC_TAIL
        LDA2(1, 1, 0)
        SYNC_HEAD
        OCT(1, 0)
        SYNC_TAIL
        LDA2(1, 1, 1)
        SYNC_HEAD
        OCT(1, 1)
        SYNC_TAIL
    }
#undef LDA2
#undef LDBA
#undef OCT

    const size_t row0 = bm + (size_t)wm * 128;
    const int col0 = (int)bn + wn * 32;
    const int c0 = lane & 31, rhi = 4 * (lane >> 5);
#pragma unroll
    for (int fm = 0; fm < 4; fm++)
#pragma unroll
        for (int reg = 0; reg < 16; reg++) {
            const size_t row = row0 + fm * 32 + (reg & 3) + 8 * (reg >> 2) + rhi;
            const float g = gate[row * NE];
            const size_t col = (size_t)col0 + c0;
            float v = (acc[fm][reg] + bias[col]) * g;
            float* p = Cptr + row * (size_t)N + col;
            *p = ACCUM ? (*p + v) : v;
        }
}

// --------- gating head: logits = gh@gw2 + gb2, softmax -> gates fp32 -------
__global__ __launch_bounds__(256) void gate_softmax_kernel(
    const f16* __restrict__ gh, const float* __restrict__ gw2,
    const float* __restrict__ gb2, float* __restrict__ gates)
{
    const int row  = blockIdx.x * 4 + (threadIdx.x >> 6);
    const int lane = threadIdx.x & 63;
    const f16* r = gh + (size_t)row * HGD;
    float acc[NE] = {};
    for (int kb = lane * 8; kb < HGD; kb += 512) {
        f16x8 v = *(const f16x8*)(r + kb);
#pragma unroll
        for (int j = 0; j < 8; j++) {
            float h = (float)v[j];
            const float* w = gw2 + (size_t)(kb + j) * NE;
#pragma unroll
            for (int e = 0; e < NE; e++) acc[e] = fmaf(h, w[e], acc[e]);
        }
    }
#pragma unroll
    for (int off = 32; off > 0; off >>= 1)
#pragma unroll
        for (int e = 0; e < NE; e++) acc[e] += __shfl_down(acc[e], off, 64);
    if (lane == 0) {
        float l[NE], m = -1e30f;
#pragma unroll
        for (int e = 0; e < NE; e++) { l[e] = acc[e] + gb2[e]; m = fmaxf(m, l[e]); }
        float s = 0.f;
#pragma unroll
        for (int e = 0; e < NE; e++) { l[e] = expf(l[e] - m); s += l[e]; }
        float inv = 1.0f / s;
#pragma unroll
        for (int e = 0; e < NE; e++) gates[(size_t)row * NE + e] = l[e] * inv;
    }
}

// ---------------------------------------------------------------------------
extern "C" void kernel_launch(void* const* d_in, const int* in_sizes, int n_in,
                              void* d_out, int out_size, void* d_ws, size_t ws_size,
                              hipStream_t stream)
{
    const float* x   = (const float*)d_in[0];
    const float* gw1 = (const float*)d_in[1];
    const float* gb1 = (const float*)d_in[2];
    const float* gw2 = (const float*)d_in[3];
    const float* gb2 = (const float*)d_in[4];
    const float* ew1 = (const float*)d_in[5];
    const float* eb1 = (const float*)d_in[6];
    const float* ew2 = (const float*)d_in[7];
    const float* eb2 = (const float*)d_in[8];
    float* out = (float*)d_out;

    // ws layout: gates(256KB) | x16(16MB) | wbuf(8MB) | hbuf(64MB, gh aliases)
    char* ws = (char*)d_ws;
    float* gates = (float*)ws;
    f16* x16  = (f16*)(ws + (256 << 10));
    f16* wbuf = x16 + (size_t)BSZ * IND;
    f16* hbuf = wbuf + (size_t)HID * IND;
    f16* gh   = hbuf;  // alias: gh fully consumed before first expert GEMM

    // 1) x -> fp16
    conv_f32_f16_kernel<<<(BSZ * IND) / (256 * 8), 256, 0, stream>>>(x, x16);

    // 2) gating GEMM1: gh = relu(x @ gw1 + gb1)   [M=8192,N=2048,K=1024]
    transpose_f32_f16_kernel<<<dim3(HGD / 64, IND / 64), 256, 0, stream>>>(
        gw1, wbuf, IND, HGD);
    gemm256_kernel<true>
        <<<(HGD / 256) * (BSZ / 256), 512, 0, stream>>>(
            x16, wbuf, gb1, gh, BSZ, HGD, IND);

    // 3) gating head + softmax -> gates
    gate_softmax_kernel<<<BSZ / 4, 256, 0, stream>>>(gh, gw2, gb2, gates);

    // 4) experts
    for (int e = 0; e < NE; e++) {
        // h = relu(x @ ew1[e] + eb1[e])   [M=8192,N=4096,K=1024]
        transpose_f32_f16_kernel<<<dim3(HID / 64, IND / 64), 256, 0, stream>>>(
            ew1 + (size_t)e * IND * HID, wbuf, IND, HID);
        gemm256_kernel<true>
            <<<(HID / 256) * (BSZ / 256), 512, 0, stream>>>(
                x16, wbuf, eb1 + (size_t)e * HID, hbuf, BSZ, HID, IND);

        // out (+)= gates[:,e] * (h @ ew2[e] + eb2[e])   [M=8192,N=1024,K=4096]
        transpose_f32_f16_kernel<<<dim3(OUTD / 64, HID / 64), 256, 0, stream>>>(
            ew2 + (size_t)e * HID * OUTD, wbuf, HID, OUTD);
        if (e == 0)
            gemmO_kernel<false>
                <<<(OUTD / 128) * (BSZ / 256), 512, 0, stream>>>(
                    hbuf, wbuf, eb2 + (size_t)e * OUTD, gates + e, out,
                    BSZ, OUTD, HID);
        else
            gemmO_kernel<true>
                <<<(OUTD / 128) * (BSZ / 256), 512, 0, stream>>>(
                    hbuf, wbuf, eb2 + (size_t)e * OUTD, gates + e, out,
                    BSZ, OUTD, HID);
    }
}

// Round 10
// 1387.692 us; speedup vs baseline: 11.8414x; 1.1439x over previous
//
#include <hip/hip_runtime.h>

// ---------------------------------------------------------------------------
// MoE forward: gating MLP + 8 dense experts + gate-weighted combine.
// All matmuls via mfma_f32_16x16x32_f16 (fp32 accum).
// r10: GEMM kernels = r4-verified (best of 7 structural variants; 0 bank
// conflicts). New: weight transposes batched into single dispatches
// (blockIdx.z = expert), behind a deterministic ws_size branch:
//   tier A (>=208MB): w1all + w2all batched   (36 -> 22 dispatches)
//   tier B (>=152MB): w2all batched only      (36 -> 29)
//   tier C: exact r4 per-expert fallback.
// ---------------------------------------------------------------------------

#define DI __device__ __forceinline__

typedef _Float16 f16;
typedef _Float16 f16x8 __attribute__((ext_vector_type(8)));
typedef float f32x4 __attribute__((ext_vector_type(4)));

constexpr int BSZ  = 8192;
constexpr int IND  = 1024;
constexpr int HID  = 4096;
constexpr int OUTD = 1024;
constexpr int NE   = 8;
constexpr int HGD  = 2048;

// ---------------- fp32 -> fp16 vectorized convert (8 elems/thread) ---------
__global__ __launch_bounds__(256) void conv_f32_f16_kernel(
    const float* __restrict__ in, f16* __restrict__ out)
{
    size_t i = ((size_t)blockIdx.x * 256 + threadIdx.x) * 8;
    const float4* p = (const float4*)(in + i);
    float4 a = p[0], b = p[1];
    f16x8 v = {(f16)a.x, (f16)a.y, (f16)a.z, (f16)a.w,
               (f16)b.x, (f16)b.y, (f16)b.z, (f16)b.w};
    *(f16x8*)(out + i) = v;
}

// -- transpose+convert: W[K][N] f32 -> Wt[N][K] f16; blockIdx.z = batch idx --
__global__ __launch_bounds__(256) void transpose_f32_f16_kernel(
    const float* __restrict__ W, f16* __restrict__ Wt, int K, int N)
{
    W  += (size_t)blockIdx.z * K * N;
    Wt += (size_t)blockIdx.z * N * K;
    __shared__ float t[64][65];
    int n0 = blockIdx.x * 64, k0 = blockIdx.y * 64;
    int tx = threadIdx.x & 63, ty = threadIdx.x >> 6;
#pragma unroll
    for (int i = 0; i < 16; i++) {
        int k = i * 4 + ty;
        t[k][tx] = W[(size_t)(k0 + k) * N + n0 + tx];
    }
    __syncthreads();
#pragma unroll
    for (int i = 0; i < 16; i++) {
        int n = i * 4 + ty;
        Wt[(size_t)(n0 + n) * K + k0 + tx] = (f16)t[tx][n];
    }
}

// ---------------- async global->LDS (16B per lane, wave-uniform dest) ------
DI void gload_lds16(const void* g, void* l)
{
    typedef const __attribute__((address_space(1))) unsigned int as1_t;
    typedef __attribute__((address_space(3))) unsigned int as3_t;
    __builtin_amdgcn_global_load_lds(
        (as1_t*)(unsigned long long)(__SIZE_TYPE__)g,
        (as3_t*)(unsigned int)(__SIZE_TYPE__)l,
        16, 0, 0);
}

// sync building blocks (rule #18: sched_barrier after lgkmcnt before MFMA)
#define SYNC_HEAD                                                              \
    __builtin_amdgcn_sched_barrier(0);                                         \
    __builtin_amdgcn_s_barrier();                                              \
    asm volatile("s_waitcnt lgkmcnt(0)" ::: "memory");                         \
    __builtin_amdgcn_sched_barrier(0);
#define SYNC_HEAD_T8                                                           \
    __builtin_amdgcn_sched_barrier(0);                                         \
    asm volatile("s_waitcnt lgkmcnt(8)");                                      \
    __builtin_amdgcn_s_barrier();                                              \
    asm volatile("s_waitcnt lgkmcnt(0)" ::: "memory");                         \
    __builtin_amdgcn_sched_barrier(0);
#define SYNC_TAIL                                                              \
    __builtin_amdgcn_sched_barrier(0);                                         \
    __builtin_amdgcn_s_barrier();                                              \
    asm volatile("" ::: "memory");

// ---------------------------------------------------------------------------
// gemm256 (r4-verified): BM=256, BN=256, BK=64, 8 waves 2Mx4N.
// ---------------------------------------------------------------------------
template <bool RELU>
__global__ __launch_bounds__(512, 2) void gemm256_kernel(
    const f16* __restrict__ A, const f16* __restrict__ Bt,
    const float* __restrict__ bias, f16* __restrict__ Cptr,
    int M, int N, int K)
{
    constexpr int BM = 256, BN = 256, BK = 64;
    constexpr int AT = BM * BK * 2, BT = BN * BK * 2;
    __shared__ __align__(16) f16 sA[2][BM * BK];
    __shared__ __align__(16) f16 sB[2][BN * BK];
    const char* sAc = (const char*)sA;
    const char* sBc = (const char*)sB;

    const int tid = threadIdx.x, wid = tid >> 6, lane = tid & 63;
    const int wm = wid >> 2, wn = wid & 3;
    const int nwg = gridDim.x, bid = blockIdx.x;
    const int wg = (bid & 7) * (nwg >> 3) + (bid >> 3);
    const int gx = N / BN;
    const size_t bm = (size_t)(wg / gx) * BM;
    const size_t bn = (size_t)(wg % gx) * BN;

    f32x4 acc[8][4] = {};

    const int rho  = tid >> 3;
    const int slot = (((tid & 7) << 4) ^ (((tid >> 3) & 7) << 4));
    const f16* pA = A  + (bm + rho) * (size_t)K + (slot >> 1);
    const f16* pB = Bt + (bn + rho) * (size_t)K + (slot >> 1);

    auto stA = [&](int b, int q, int T) {
        gload_lds16(pA + ((size_t)q * 64) * K + (size_t)T * BK,
                    (char*)sAc + b * AT + q * 8192 + wid * 1024);
    };
    auto stB = [&](int b, int q, int T) {
        gload_lds16(pB + ((size_t)q * 64) * K + (size_t)T * BK,
                    (char*)sBc + b * BT + q * 8192 + wid * 1024);
    };

    int offA0[8], offB0[4];
#pragma unroll
    for (int f = 0; f < 8; f++) {
        int r = wm * 128 + f * 16 + (lane & 15);
        offA0[f] = r * 128 + ((((lane >> 4) << 4)) ^ ((r & 7) << 4));
    }
#pragma unroll
    for (int f = 0; f < 4; f++) {
        int r = wn * 64 + f * 16 + (lane & 15);
        offB0[f] = r * 128 + ((((lane >> 4) << 4)) ^ ((r & 7) << 4));
    }

    f16x8 av[4][2], bv0[2][2], bv1[2][2];

#define LDAQ(B, MH)                                                            \
    _Pragma("unroll") for (int f = 0; f < 4; f++)                              \
    _Pragma("unroll") for (int kc = 0; kc < 2; kc++)                           \
        av[f][kc] = *(const f16x8*)(sAc + (B) * AT + (offA0[(MH)*4+f] ^ (kc << 6)));
#define LDBH(B, NH, BV)                                                        \
    _Pragma("unroll") for (int f = 0; f < 2; f++)                              \
    _Pragma("unroll") for (int kc = 0; kc < 2; kc++)                           \
        BV[f][kc] = *(const f16x8*)(sBc + (B) * BT + (offB0[(NH)*2+f] ^ (kc << 6)));
#define QUAD(MH, NH, BV)                                                       \
    __builtin_amdgcn_s_setprio(1);                                             \
    _Pragma("unroll") for (int f = 0; f < 4; f++)                              \
    _Pragma("unroll") for (int g = 0; g < 2; g++)                              \
    _Pragma("unroll") for (int kc = 0; kc < 2; kc++)                           \
        acc[(MH)*4+f][(NH)*2+g] = __builtin_amdgcn_mfma_f32_16x16x32_f16(      \
            av[f][kc], BV[g][kc], acc[(MH)*4+f][(NH)*2+g], 0, 0, 0);           \
    __builtin_amdgcn_s_setprio(0);

    const int NT = K / BK, NI = NT / 2;

    stA(0,0,0); stA(0,2,0); stB(0,0,0); stB(0,1,0); stB(0,2,0); stB(0,3,0);
    stA(0,1,0); stA(0,3,0);
    stA(1,0,1); stA(1,2,1); stB(1,0,1); stB(1,1,1); stB(1,2,1); stB(1,3,1);
    asm volatile("s_waitcnt vmcnt(6)");
    __builtin_amdgcn_s_barrier();
    asm volatile("" ::: "memory");

    for (int i = 0; i < NI - 1; ++i) {
        const int t = 2 * i;
        LDAQ(0, 0) LDBH(0, 0, bv0)
        stA(1, 1, t + 1); stA(1, 3, t + 1);
        SYNC_HEAD_T8
        QUAD(0, 0, bv0)
        SYNC_TAIL
        LDBH(0, 1, bv1)
        stA(0, 0, t + 2); stA(0, 2, t + 2);
        SYNC_HEAD
        QUAD(0, 1, bv1)
        SYNC_TAIL
        LDAQ(0, 1)
        stB(0, 0, t + 2); stB(0, 1, t + 2);
        SYNC_HEAD
        QUAD(1, 1, bv1)
        SYNC_TAIL
        stB(0, 2, t + 2); stB(0, 3, t + 2);
        SYNC_HEAD
        QUAD(1, 0, bv0)
        asm volatile("s_waitcnt vmcnt(6)");
        SYNC_TAIL
        LDAQ(1, 0) LDBH(1, 0, bv0)
        stA(0, 1, t + 2); stA(0, 3, t + 2);
        SYNC_HEAD_T8
        QUAD(0, 0, bv0)
        SYNC_TAIL
        LDBH(1, 1, bv1)
        stA(1, 0, t + 3); stA(1, 2, t + 3);
        SYNC_HEAD
        QUAD(0, 1, bv1)
        SYNC_TAIL
        LDAQ(1, 1)
        stB(1, 0, t + 3); stB(1, 1, t + 3);
        SYNC_HEAD
        QUAD(1, 1, bv1)
        SYNC_TAIL
        stB(1, 2, t + 3); stB(1, 3, t + 3);
        SYNC_HEAD
        QUAD(1, 0, bv0)
        asm volatile("s_waitcnt vmcnt(6)");
        SYNC_TAIL
    }
    {   // final iteration (tiles NT-2, NT-1)
        LDAQ(0, 0) LDBH(0, 0, bv0)
        stA(1, 1, NT - 1); stA(1, 3, NT - 1);
        SYNC_HEAD_T8
        QUAD(0, 0, bv0)
        SYNC_TAIL
        LDBH(0, 1, bv1)
        SYNC_HEAD
        QUAD(0, 1, bv1)
        SYNC_TAIL
        LDAQ(0, 1)
        SYNC_HEAD
        QUAD(1, 1, bv1)
        SYNC_TAIL
        SYNC_HEAD
        QUAD(1, 0, bv0)
        asm volatile("s_waitcnt vmcnt(0)");
        SYNC_TAIL
        LDAQ(1, 0) LDBH(1, 0, bv0)
        SYNC_HEAD
        QUAD(0, 0, bv0)
        SYNC_TAIL
        LDBH(1, 1, bv1)
        SYNC_HEAD
        QUAD(0, 1, bv1)
        SYNC_TAIL
        LDAQ(1, 1)
        SYNC_HEAD
        QUAD(1, 1, bv1)
        SYNC_TAIL
        SYNC_HEAD
        QUAD(1, 0, bv0)
        SYNC_TAIL
    }
#undef LDAQ
#undef LDBH
#undef QUAD

    const size_t row0 = bm + (size_t)wm * 128;
    const int col0 = (int)bn + wn * 64;
    const int c0 = lane & 15, r0 = (lane >> 4) * 4;
#pragma unroll
    for (int fm = 0; fm < 8; fm++)
#pragma unroll
        for (int r = 0; r < 4; r++) {
            const size_t row = row0 + fm * 16 + r0 + r;
#pragma unroll
            for (int n = 0; n < 4; n++) {
                const size_t col = (size_t)col0 + n * 16 + c0;
                float v = acc[fm][n][r] + bias[col];
                if constexpr (RELU) v = fmaxf(v, 0.0f);
                Cptr[row * (size_t)N + col] = (f16)v;
            }
        }
}

// ---------------------------------------------------------------------------
// gemmO (r4-verified): BM=256, BN=128, BK=64, 8 waves 2Mx4N (wave 128x32).
// ---------------------------------------------------------------------------
template <bool ACCUM>
__global__ __launch_bounds__(512, 2) void gemmO_kernel(
    const f16* __restrict__ A, const f16* __restrict__ Bt,
    const float* __restrict__ bias, const float* __restrict__ gate,
    float* __restrict__ Cptr, int M, int N, int K)
{
    constexpr int BM = 256, BN = 128, BK = 64;
    constexpr int AT = BM * BK * 2, BT = BN * BK * 2;   // 32768 / 16384
    __shared__ __align__(16) f16 sA[2][BM * BK];
    __shared__ __align__(16) f16 sB[2][BN * BK];
    const char* sAc = (const char*)sA;
    const char* sBc = (const char*)sB;

    const int tid = threadIdx.x, wid = tid >> 6, lane = tid & 63;
    const int wm = wid >> 2, wn = wid & 3;
    const int nwg = gridDim.x, bid = blockIdx.x;
    const int wg = (bid & 7) * (nwg >> 3) + (bid >> 3);
    const int gx = N / BN;
    const size_t bm = (size_t)(wg / gx) * BM;
    const size_t bn = (size_t)(wg % gx) * BN;

    f32x4 acc[8][2] = {};

    const int rho  = tid >> 3;
    const int slot = (((tid & 7) << 4) ^ (((tid >> 3) & 7) << 4));
    const f16* pA = A  + (bm + rho) * (size_t)K + (slot >> 1);
    const f16* pB = Bt + (bn + rho) * (size_t)K + (slot >> 1);

    auto stA = [&](int b, int q, int T) {
        gload_lds16(pA + ((size_t)q * 64) * K + (size_t)T * BK,
                    (char*)sAc + b * AT + q * 8192 + wid * 1024);
    };
    auto stB = [&](int b, int q, int T) {
        gload_lds16(pB + ((size_t)q * 64) * K + (size_t)T * BK,
                    (char*)sBc + b * BT + q * 8192 + wid * 1024);
    };

    int offA0[8], offB0[2];
#pragma unroll
    for (int f = 0; f < 8; f++) {
        int r = wm * 128 + f * 16 + (lane & 15);
        offA0[f] = r * 128 + ((((lane >> 4) << 4)) ^ ((r & 7) << 4));
    }
#pragma unroll
    for (int f = 0; f < 2; f++) {
        int r = wn * 32 + f * 16 + (lane & 15);
        offB0[f] = r * 128 + ((((lane >> 4) << 4)) ^ ((r & 7) << 4));
    }

    f16x8 av[4], bv[2][2];

#define LDA4(B, MH, KC)                                                        \
    _Pragma("unroll") for (int f = 0; f < 4; f++)                              \
        av[f] = *(const f16x8*)(sAc + (B) * AT + (offA0[(MH)*4+f] ^ ((KC) << 6)));
#define LDBA(B)                                                                \
    _Pragma("unroll") for (int f = 0; f < 2; f++)                              \
    _Pragma("unroll") for (int kc = 0; kc < 2; kc++)                           \
        bv[f][kc] = *(const f16x8*)(sBc + (B) * BT + (offB0[f] ^ (kc << 6)));
#define OCT(MH, KC)                                                            \
    __builtin_amdgcn_s_setprio(1);                                             \
    _Pragma("unroll") for (int f = 0; f < 4; f++)                              \
    _Pragma("unroll") for (int g = 0; g < 2; g++)                              \
        acc[(MH)*4+f][g] = __builtin_amdgcn_mfma_f32_16x16x32_f16(             \
            av[f], bv[g][KC], acc[(MH)*4+f][g], 0, 0, 0);                      \
    __builtin_amdgcn_s_setprio(0);

    const int NT = K / BK, NI = NT / 2;

    stA(0,0,0); stA(0,2,0); stB(0,0,0); stB(0,1,0); stA(0,1,0); stA(0,3,0);
    stA(1,0,1); stA(1,2,1); stB(1,0,1); stB(1,1,1);
    asm volatile("s_waitcnt vmcnt(4)");
    __builtin_amdgcn_s_barrier();
    asm volatile("" ::: "memory");

    for (int i = 0; i < NI - 1; ++i) {
        const int t = 2 * i;
        LDA4(0, 0, 0) LDBA(0)
        stA(1, 1, t + 1); stA(1, 3, t + 1);
        SYNC_HEAD
        OCT(0, 0)
        SYNC_TAIL
        LDA4(0, 0, 1)
        SYNC_HEAD
        OCT(0, 1)
        SYNC_TAIL
        LDA4(0, 1, 0)
        stA(0, 0, t + 2); stA(0, 2, t + 2);
        SYNC_HEAD
        OCT(1, 0)
        SYNC_TAIL
        LDA4(0, 1, 1)
        stB(0, 0, t + 2); stB(0, 1, t + 2);
        SYNC_HEAD
        OCT(1, 1)
        asm volatile("s_waitcnt vmcnt(4)");
        SYNC_TAIL
        LDA4(1, 0, 0) LDBA(1)
        stA(0, 1, t + 2); stA(0, 3, t + 2);
        SYNC_HEAD
        OCT(0, 0)
        SYNC_TAIL
        LDA4(1, 0, 1)
        SYNC_HEAD
        OCT(0, 1)
        SYNC_TAIL
        LDA4(1, 1, 0)
        stA(1, 0, t + 3); stA(1, 2, t + 3);
        SYNC_HEAD
        OCT(1, 0)
        SYNC_TAIL
        LDA4(1, 1, 1)
        stB(1, 0, t + 3); stB(1, 1, t + 3);
        SYNC_HEAD
        OCT(1, 1)
        asm volatile("s_waitcnt vmcnt(4)");
        SYNC_TAIL
    }
    {   // final iteration
        LDA4(0, 0, 0) LDBA(0)
        stA(1, 1, NT - 1); stA(1, 3, NT - 1);
        SYNC_HEAD
        OCT(0, 0)
        SYNC_TAIL
        LDA4(0, 0, 1)
        SYNC_HEAD
        OCT(0, 1)
        SYNC_TAIL
        LDA4(0, 1, 0)
        SYNC_HEAD
        OCT(1, 0)
        SYNC_TAIL
        LDA4(0, 1, 1)
        SYNC_HEAD
        OCT(1, 1)
        asm volatile("s_waitcnt vmcnt(0)");
        SYNC_TAIL
        LDA4(1, 0, 0) LDBA(1)
        SYNC_HEAD
        OCT(0, 0)
        SYNC_TAIL
        LDA4(1, 0, 1)
        SYNC_HEAD
        OCT(0, 1)
        SYNC_TAIL
        LDA4(1, 1, 0)
        SYNC_HEAD
        OCT(1, 0)
        SYNC_TAIL
        LDA4(1, 1, 1)
        SYNC_HEAD
        OCT(1, 1)
        SYNC_TAIL
    }
#undef LDA4
#undef LDBA
#undef OCT

    const size_t row0 = bm + (size_t)wm * 128;
    const int col0 = (int)bn + wn * 32;
    const int c0 = lane & 15, r0 = (lane >> 4) * 4;
#pragma unroll
    for (int fm = 0; fm < 8; fm++)
#pragma unroll
        for (int r = 0; r < 4; r++) {
            const size_t row = row0 + fm * 16 + r0 + r;
            const float g = gate[row * NE];
#pragma unroll
            for (int n = 0; n < 2; n++) {
                const size_t col = (size_t)col0 + n * 16 + c0;
                float v = (acc[fm][n][r] + bias[col]) * g;
                float* p = Cptr + row * (size_t)N + col;
                *p = ACCUM ? (*p + v) : v;
            }
        }
}

// --------- gating head: logits = gh@gw2 + gb2, softmax -> gates fp32 -------
__global__ __launch_bounds__(256) void gate_softmax_kernel(
    const f16* __restrict__ gh, const float* __restrict__ gw2,
    const float* __restrict__ gb2, float* __restrict__ gates)
{
    const int row  = blockIdx.x * 4 + (threadIdx.x >> 6);
    const int lane = threadIdx.x & 63;
    const f16* r = gh + (size_t)row * HGD;
    float acc[NE] = {};
    for (int kb = lane * 8; kb < HGD; kb += 512) {
        f16x8 v = *(const f16x8*)(r + kb);
#pragma unroll
        for (int j = 0; j < 8; j++) {
            float h = (float)v[j];
            const float* w = gw2 + (size_t)(kb + j) * NE;
#pragma unroll
            for (int e = 0; e < NE; e++) acc[e] = fmaf(h, w[e], acc[e]);
        }
    }
#pragma unroll
    for (int off = 32; off > 0; off >>= 1)
#pragma unroll
        for (int e = 0; e < NE; e++) acc[e] += __shfl_down(acc[e], off, 64);
    if (lane == 0) {
        float l[NE], m = -1e30f;
#pragma unroll
        for (int e = 0; e < NE; e++) { l[e] = acc[e] + gb2[e]; m = fmaxf(m, l[e]); }
        float s = 0.f;
#pragma unroll
        for (int e = 0; e < NE; e++) { l[e] = expf(l[e] - m); s += l[e]; }
        float inv = 1.0f / s;
#pragma unroll
        for (int e = 0; e < NE; e++) gates[(size_t)row * NE + e] = l[e] * inv;
    }
}

// ---------------------------------------------------------------------------
extern "C" void kernel_launch(void* const* d_in, const int* in_sizes, int n_in,
                              void* d_out, int out_size, void* d_ws, size_t ws_size,
                              hipStream_t stream)
{
    const float* x   = (const float*)d_in[0];
    const float* gw1 = (const float*)d_in[1];
    const float* gb1 = (const float*)d_in[2];
    const float* gw2 = (const float*)d_in[3];
    const float* gb2 = (const float*)d_in[4];
    const float* ew1 = (const float*)d_in[5];
    const float* eb1 = (const float*)d_in[6];
    const float* ew2 = (const float*)d_in[7];
    const float* eb2 = (const float*)d_in[8];
    float* out = (float*)d_out;

    const size_t SZ_GATES = 256 << 10;
    const size_t SZ_X16   = (size_t)BSZ * IND * 2;     // 16 MB
    const size_t SZ_WBUF  = (size_t)HID * IND * 2;     //  8 MB
    const size_t SZ_W1ALL = (size_t)NE * HID * IND * 2;  // 64 MB
    const size_t SZ_W2ALL = (size_t)NE * OUTD * HID * 2; // 64 MB
    const size_t SZ_HBUF  = (size_t)BSZ * HID * 2;     // 64 MB
    const size_t NEED_A = SZ_GATES + SZ_X16 + SZ_W1ALL + SZ_W2ALL + SZ_HBUF;
    const size_t NEED_B = SZ_GATES + SZ_X16 + SZ_WBUF + SZ_W2ALL + SZ_HBUF;

    char* p = (char*)d_ws;
    float* gates = (float*)p;  p += SZ_GATES;
    f16* x16 = (f16*)p;        p += SZ_X16;

    // 1) x -> fp16 (all tiers)
    conv_f32_f16_kernel<<<(BSZ * IND) / (256 * 8), 256, 0, stream>>>(x, x16);

    if (ws_size >= NEED_A) {
        // ---- tier A: both weight sets batch-transposed ----
        f16* w1all = (f16*)p;  p += SZ_W1ALL;
        f16* w2all = (f16*)p;  p += SZ_W2ALL;
        f16* hbuf  = (f16*)p;
        f16* gh    = hbuf;   // gh consumed before first H GEMM

        // gating (gw1 transposed into w1all scratch; overwritten later)
        transpose_f32_f16_kernel<<<dim3(HGD / 64, IND / 64, 1), 256, 0, stream>>>(
            gw1, w1all, IND, HGD);
        gemm256_kernel<true><<<(HGD / 256) * (BSZ / 256), 512, 0, stream>>>(
            x16, w1all, gb1, gh, BSZ, HGD, IND);
        gate_softmax_kernel<<<BSZ / 4, 256, 0, stream>>>(gh, gw2, gb2, gates);

        // batched weight transposes (one dispatch each)
        transpose_f32_f16_kernel<<<dim3(HID / 64, IND / 64, NE), 256, 0, stream>>>(
            ew1, w1all, IND, HID);
        transpose_f32_f16_kernel<<<dim3(OUTD / 64, HID / 64, NE), 256, 0, stream>>>(
            ew2, w2all, HID, OUTD);

        for (int e = 0; e < NE; e++) {
            gemm256_kernel<true><<<(HID / 256) * (BSZ / 256), 512, 0, stream>>>(
                x16, w1all + (size_t)e * HID * IND, eb1 + (size_t)e * HID,
                hbuf, BSZ, HID, IND);
            if (e == 0)
                gemmO_kernel<false><<<(OUTD / 128) * (BSZ / 256), 512, 0, stream>>>(
                    hbuf, w2all + (size_t)e * OUTD * HID, eb2 + (size_t)e * OUTD,
                    gates + e, out, BSZ, OUTD, HID);
            else
                gemmO_kernel<true><<<(OUTD / 128) * (BSZ / 256), 512, 0, stream>>>(
                    hbuf, w2all + (size_t)e * OUTD * HID, eb2 + (size_t)e * OUTD,
                    gates + e, out, BSZ, OUTD, HID);
        }
    } else if (ws_size >= NEED_B) {
        // ---- tier B: only ew2 batch-transposed ----
        f16* wbuf  = (f16*)p;  p += SZ_WBUF;
        f16* w2all = (f16*)p;  p += SZ_W2ALL;
        f16* hbuf  = (f16*)p;
        f16* gh    = hbuf;

        transpose_f32_f16_kernel<<<dim3(HGD / 64, IND / 64, 1), 256, 0, stream>>>(
            gw1, wbuf, IND, HGD);
        gemm256_kernel<true><<<(HGD / 256) * (BSZ / 256), 512, 0, stream>>>(
            x16, wbuf, gb1, gh, BSZ, HGD, IND);
        gate_softmax_kernel<<<BSZ / 4, 256, 0, stream>>>(gh, gw2, gb2, gates);

        transpose_f32_f16_kernel<<<dim3(OUTD / 64, HID / 64, NE), 256, 0, stream>>>(
            ew2, w2all, HID, OUTD);

        for (int e = 0; e < NE; e++) {
            transpose_f32_f16_kernel<<<dim3(HID / 64, IND / 64, 1), 256, 0, stream>>>(
                ew1 + (size_t)e * IND * HID, wbuf, IND, HID);
            gemm256_kernel<true><<<(HID / 256) * (BSZ / 256), 512, 0, stream>>>(
                x16, wbuf, eb1 + (size_t)e * HID, hbuf, BSZ, HID, IND);
            if (e == 0)
                gemmO_kernel<false><<<(OUTD / 128) * (BSZ / 256), 512, 0, stream>>>(
                    hbuf, w2all + (size_t)e * OUTD * HID, eb2 + (size_t)e * OUTD,
                    gates + e, out, BSZ, OUTD, HID);
            else
                gemmO_kernel<true><<<(OUTD / 128) * (BSZ / 256), 512, 0, stream>>>(
                    hbuf, w2all + (size_t)e * OUTD * HID, eb2 + (size_t)e * OUTD,
                    gates + e, out, BSZ, OUTD, HID);
        }
    } else {
        // ---- tier C: exact r4 fallback ----
        f16* wbuf = (f16*)p;   p += SZ_WBUF;
        f16* hbuf = (f16*)p;
        f16* gh   = hbuf;

        transpose_f32_f16_kernel<<<dim3(HGD / 64, IND / 64, 1), 256, 0, stream>>>(
            gw1, wbuf, IND, HGD);
        gemm256_kernel<true><<<(HGD / 256) * (BSZ / 256), 512, 0, stream>>>(
            x16, wbuf, gb1, gh, BSZ, HGD, IND);
        gate_softmax_kernel<<<BSZ / 4, 256, 0, stream>>>(gh, gw2, gb2, gates);

        for (int e = 0; e < NE; e++) {
            transpose_f32_f16_kernel<<<dim3(HID / 64, IND / 64, 1), 256, 0, stream>>>(
                ew1 + (size_t)e * IND * HID, wbuf, IND, HID);
            gemm256_kernel<true><<<(HID / 256) * (BSZ / 256), 512, 0, stream>>>(
                x16, wbuf, eb1 + (size_t)e * HID, hbuf, BSZ, HID, IND);

            transpose_f32_f16_kernel<<<dim3(OUTD / 64, HID / 64, 1), 256, 0, stream>>>(
                ew2 + (size_t)e * HID * OUTD, wbuf, HID, OUTD);
            if (e == 0)
                gemmO_kernel<false><<<(OUTD / 128) * (BSZ / 256), 512, 0, stream>>>(
                    hbuf, wbuf, eb2 + (size_t)e * OUTD, gates + e, out,
                    BSZ, OUTD, HID);
            else
                gemmO_kernel<true><<<(OUTD / 128) * (BSZ / 256), 512, 0, stream>>>(
                    hbuf, wbuf, eb2 + (size_t)e * OUTD, gates + e, out,
                    BSZ, OUTD, HID);
        }
    }
}

// Round 11
// 1318.997 us; speedup vs baseline: 12.4581x; 1.0521x over previous
//
#include <hip/hip_runtime.h>

// ---------------------------------------------------------------------------
// MoE forward: gating MLP + 8 dense experts + gate-weighted combine.
// r11: gate folded into hs (hs_e = gate_e*relu(x@w1_e+b1_e), exact for
// gate>=0); G experts grouped per OUT GEMM (K = G*4096) with bias-dot
// epilogue sum_j gate_j*eb2_j. Cuts out-RMW HBM traffic (480->96MB @ G=4),
// dispatch tails, and amortizes gemmO prologue. GEMM inner loops are the
// r4-verified schedules (0 bank conflicts); only epilogues/strides changed.
// ws_size tiers: G=4 (400MB) / G=2 (272MB) / G=1 (=r10 tier A, 208MB) / r4.
// ---------------------------------------------------------------------------

#define DI __device__ __forceinline__

typedef _Float16 f16;
typedef _Float16 f16x8 __attribute__((ext_vector_type(8)));
typedef float f32x4 __attribute__((ext_vector_type(4)));

constexpr int BSZ  = 8192;
constexpr int IND  = 1024;
constexpr int HID  = 4096;
constexpr int OUTD = 1024;
constexpr int NE   = 8;
constexpr int HGD  = 2048;

// ---------------- fp32 -> fp16 vectorized convert (8 elems/thread) ---------
__global__ __launch_bounds__(256) void conv_f32_f16_kernel(
    const float* __restrict__ in, f16* __restrict__ out)
{
    size_t i = ((size_t)blockIdx.x * 256 + threadIdx.x) * 8;
    const float4* p = (const float4*)(in + i);
    float4 a = p[0], b = p[1];
    f16x8 v = {(f16)a.x, (f16)a.y, (f16)a.z, (f16)a.w,
               (f16)b.x, (f16)b.y, (f16)b.z, (f16)b.w};
    *(f16x8*)(out + i) = v;
}

// transpose+convert: W[z][K][N] f32 -> Wt[z*zstride + n*ldo + z*kostep + k]
__global__ __launch_bounds__(256) void transpose_f32_f16_kernel(
    const float* __restrict__ W, f16* __restrict__ Wt, int K, int N,
    int ldo, size_t zstride, int kostep)
{
    const int z = blockIdx.z;
    W += (size_t)z * K * N;
    f16* base = Wt + (size_t)z * zstride + (size_t)z * kostep;
    __shared__ float t[64][65];
    int n0 = blockIdx.x * 64, k0 = blockIdx.y * 64;
    int tx = threadIdx.x & 63, ty = threadIdx.x >> 6;
#pragma unroll
    for (int i = 0; i < 16; i++) {
        int k = i * 4 + ty;
        t[k][tx] = W[(size_t)(k0 + k) * N + n0 + tx];
    }
    __syncthreads();
#pragma unroll
    for (int i = 0; i < 16; i++) {
        int n = i * 4 + ty;
        base[(size_t)(n0 + n) * ldo + k0 + tx] = (f16)t[tx][n];
    }
}

// ---------------- async global->LDS (16B per lane, wave-uniform dest) ------
DI void gload_lds16(const void* g, void* l)
{
    typedef const __attribute__((address_space(1))) unsigned int as1_t;
    typedef __attribute__((address_space(3))) unsigned int as3_t;
    __builtin_amdgcn_global_load_lds(
        (as1_t*)(unsigned long long)(__SIZE_TYPE__)g,
        (as3_t*)(unsigned int)(__SIZE_TYPE__)l,
        16, 0, 0);
}

// sync building blocks (rule #18: sched_barrier after lgkmcnt before MFMA)
#define SYNC_HEAD                                                              \
    __builtin_amdgcn_sched_barrier(0);                                         \
    __builtin_amdgcn_s_barrier();                                              \
    asm volatile("s_waitcnt lgkmcnt(0)" ::: "memory");                         \
    __builtin_amdgcn_sched_barrier(0);
#define SYNC_HEAD_T8                                                           \
    __builtin_amdgcn_sched_barrier(0);                                         \
    asm volatile("s_waitcnt lgkmcnt(8)");                                      \
    __builtin_amdgcn_s_barrier();                                              \
    asm volatile("s_waitcnt lgkmcnt(0)" ::: "memory");                         \
    __builtin_amdgcn_sched_barrier(0);
#define SYNC_TAIL                                                              \
    __builtin_amdgcn_sched_barrier(0);                                         \
    __builtin_amdgcn_s_barrier();                                              \
    asm volatile("" ::: "memory");

// ---------------------------------------------------------------------------
// gemm256 (r4-verified loop): BM=256, BN=256, BK=64, 8 waves 2Mx4N.
// blockIdx.z = sub-expert: Bt += z*N*K, bias += z*N, C col base z*N.
// GSCALE: v = relu(v) * gate[row*NE + e0 + z]. C: [row*ldc + z*N + col] f16.
// ---------------------------------------------------------------------------
template <bool RELU, bool GSCALE>
__global__ __launch_bounds__(512, 2) void gemm256_kernel(
    const f16* __restrict__ A, const f16* __restrict__ Bt,
    const float* __restrict__ bias, const float* __restrict__ gate,
    f16* __restrict__ Cptr, int M, int N, int K, int ldc, int e0)
{
    constexpr int BM = 256, BN = 256, BK = 64;
    constexpr int AT = BM * BK * 2, BT = BN * BK * 2;
    __shared__ __align__(16) f16 sA[2][BM * BK];
    __shared__ __align__(16) f16 sB[2][BN * BK];
    const char* sAc = (const char*)sA;
    const char* sBc = (const char*)sB;

    const int z = blockIdx.z;
    Bt   += (size_t)z * N * K;
    bias += (size_t)z * N;

    const int tid = threadIdx.x, wid = tid >> 6, lane = tid & 63;
    const int wm = wid >> 2, wn = wid & 3;
    const int nwg = gridDim.x, bid = blockIdx.x;
    const int wg = (bid & 7) * (nwg >> 3) + (bid >> 3);
    const int gx = N / BN;
    const size_t bm = (size_t)(wg / gx) * BM;
    const size_t bn = (size_t)(wg % gx) * BN;

    f32x4 acc[8][4] = {};

    const int rho  = tid >> 3;
    const int slot = (((tid & 7) << 4) ^ (((tid >> 3) & 7) << 4));
    const f16* pA = A  + (bm + rho) * (size_t)K + (slot >> 1);
    const f16* pB = Bt + (bn + rho) * (size_t)K + (slot >> 1);

    auto stA = [&](int b, int q, int T) {
        gload_lds16(pA + ((size_t)q * 64) * K + (size_t)T * BK,
                    (char*)sAc + b * AT + q * 8192 + wid * 1024);
    };
    auto stB = [&](int b, int q, int T) {
        gload_lds16(pB + ((size_t)q * 64) * K + (size_t)T * BK,
                    (char*)sBc + b * BT + q * 8192 + wid * 1024);
    };

    int offA0[8], offB0[4];
#pragma unroll
    for (int f = 0; f < 8; f++) {
        int r = wm * 128 + f * 16 + (lane & 15);
        offA0[f] = r * 128 + ((((lane >> 4) << 4)) ^ ((r & 7) << 4));
    }
#pragma unroll
    for (int f = 0; f < 4; f++) {
        int r = wn * 64 + f * 16 + (lane & 15);
        offB0[f] = r * 128 + ((((lane >> 4) << 4)) ^ ((r & 7) << 4));
    }

    f16x8 av[4][2], bv0[2][2], bv1[2][2];

#define LDAQ(B, MH)                                                            \
    _Pragma("unroll") for (int f = 0; f < 4; f++)                              \
    _Pragma("unroll") for (int kc = 0; kc < 2; kc++)                           \
        av[f][kc] = *(const f16x8*)(sAc + (B) * AT + (offA0[(MH)*4+f] ^ (kc << 6)));
#define LDBH(B, NH, BV)                                                        \
    _Pragma("unroll") for (int f = 0; f < 2; f++)                              \
    _Pragma("unroll") for (int kc = 0; kc < 2; kc++)                           \
        BV[f][kc] = *(const f16x8*)(sBc + (B) * BT + (offB0[(NH)*2+f] ^ (kc << 6)));
#define QUAD(MH, NH, BV)                                                       \
    __builtin_amdgcn_s_setprio(1);                                             \
    _Pragma("unroll") for (int f = 0; f < 4; f++)                              \
    _Pragma("unroll") for (int g = 0; g < 2; g++)                              \
    _Pragma("unroll") for (int kc = 0; kc < 2; kc++)                           \
        acc[(MH)*4+f][(NH)*2+g] = __builtin_amdgcn_mfma_f32_16x16x32_f16(      \
            av[f][kc], BV[g][kc], acc[(MH)*4+f][(NH)*2+g], 0, 0, 0);           \
    __builtin_amdgcn_s_setprio(0);

    const int NT = K / BK, NI = NT / 2;

    stA(0,0,0); stA(0,2,0); stB(0,0,0); stB(0,1,0); stB(0,2,0); stB(0,3,0);
    stA(0,1,0); stA(0,3,0);
    stA(1,0,1); stA(1,2,1); stB(1,0,1); stB(1,1,1); stB(1,2,1); stB(1,3,1);
    asm volatile("s_waitcnt vmcnt(6)");
    __builtin_amdgcn_s_barrier();
    asm volatile("" ::: "memory");

    for (int i = 0; i < NI - 1; ++i) {
        const int t = 2 * i;
        LDAQ(0, 0) LDBH(0, 0, bv0)
        stA(1, 1, t + 1); stA(1, 3, t + 1);
        SYNC_HEAD_T8
        QUAD(0, 0, bv0)
        SYNC_TAIL
        LDBH(0, 1, bv1)
        stA(0, 0, t + 2); stA(0, 2, t + 2);
        SYNC_HEAD
        QUAD(0, 1, bv1)
        SYNC_TAIL
        LDAQ(0, 1)
        stB(0, 0, t + 2); stB(0, 1, t + 2);
        SYNC_HEAD
        QUAD(1, 1, bv1)
        SYNC_TAIL
        stB(0, 2, t + 2); stB(0, 3, t + 2);
        SYNC_HEAD
        QUAD(1, 0, bv0)
        asm volatile("s_waitcnt vmcnt(6)");
        SYNC_TAIL
        LDAQ(1, 0) LDBH(1, 0, bv0)
        stA(0, 1, t + 2); stA(0, 3, t + 2);
        SYNC_HEAD_T8
        QUAD(0, 0, bv0)
        SYNC_TAIL
        LDBH(1, 1, bv1)
        stA(1, 0, t + 3); stA(1, 2, t + 3);
        SYNC_HEAD
        QUAD(0, 1, bv1)
        SYNC_TAIL
        LDAQ(1, 1)
        stB(1, 0, t + 3); stB(1, 1, t + 3);
        SYNC_HEAD
        QUAD(1, 1, bv1)
        SYNC_TAIL
        stB(1, 2, t + 3); stB(1, 3, t + 3);
        SYNC_HEAD
        QUAD(1, 0, bv0)
        asm volatile("s_waitcnt vmcnt(6)");
        SYNC_TAIL
    }
    {   // final iteration (tiles NT-2, NT-1)
        LDAQ(0, 0) LDBH(0, 0, bv0)
        stA(1, 1, NT - 1); stA(1, 3, NT - 1);
        SYNC_HEAD_T8
        QUAD(0, 0, bv0)
        SYNC_TAIL
        LDBH(0, 1, bv1)
        SYNC_HEAD
        QUAD(0, 1, bv1)
        SYNC_TAIL
        LDAQ(0, 1)
        SYNC_HEAD
        QUAD(1, 1, bv1)
        SYNC_TAIL
        SYNC_HEAD
        QUAD(1, 0, bv0)
        asm volatile("s_waitcnt vmcnt(0)");
        SYNC_TAIL
        LDAQ(1, 0) LDBH(1, 0, bv0)
        SYNC_HEAD
        QUAD(0, 0, bv0)
        SYNC_TAIL
        LDBH(1, 1, bv1)
        SYNC_HEAD
        QUAD(0, 1, bv1)
        SYNC_TAIL
        LDAQ(1, 1)
        SYNC_HEAD
        QUAD(1, 1, bv1)
        SYNC_TAIL
        SYNC_HEAD
        QUAD(1, 0, bv0)
        SYNC_TAIL
    }
#undef LDAQ
#undef LDBH
#undef QUAD

    const size_t row0 = bm + (size_t)wm * 128;
    const int col0 = (int)bn + wn * 64;
    const int c0 = lane & 15, r0 = (lane >> 4) * 4;
    f16* Cz = Cptr + (size_t)z * N;
#pragma unroll
    for (int fm = 0; fm < 8; fm++)
#pragma unroll
        for (int r = 0; r < 4; r++) {
            const size_t row = row0 + fm * 16 + r0 + r;
            float g = 1.0f;
            if constexpr (GSCALE) g = gate[row * NE + e0 + z];
#pragma unroll
            for (int n = 0; n < 4; n++) {
                const size_t col = (size_t)col0 + n * 16 + c0;
                float v = acc[fm][n][r] + bias[col];
                if constexpr (RELU) v = fmaxf(v, 0.0f);
                if constexpr (GSCALE) v *= g;
                Cz[row * (size_t)ldc + col] = (f16)v;
            }
        }
}

// ---------------------------------------------------------------------------
// gemmO (r4-verified loop): BM=256, BN=128, BK=64, 8 waves 2Mx4N.
// B row stride = ldb (>= K). GN==0: legacy (acc+bias[col])*gate[row*NE].
// GN>0: v = acc + sum_{j<GN} gate[row*NE+e0+j]*bias[(e0+j)*N+col].
// ---------------------------------------------------------------------------
template <bool ACCUM, int GN>
__global__ __launch_bounds__(512, 2) void gemmO_kernel(
    const f16* __restrict__ A, const f16* __restrict__ Bt,
    const float* __restrict__ bias, const float* __restrict__ gate,
    float* __restrict__ Cptr, int M, int N, int K, int ldb, int e0)
{
    constexpr int BM = 256, BN = 128, BK = 64;
    constexpr int AT = BM * BK * 2, BT = BN * BK * 2;
    __shared__ __align__(16) f16 sA[2][BM * BK];
    __shared__ __align__(16) f16 sB[2][BN * BK];
    const char* sAc = (const char*)sA;
    const char* sBc = (const char*)sB;

    const int tid = threadIdx.x, wid = tid >> 6, lane = tid & 63;
    const int wm = wid >> 2, wn = wid & 3;
    const int nwg = gridDim.x, bid = blockIdx.x;
    const int wg = (bid & 7) * (nwg >> 3) + (bid >> 3);
    const int gx = N / BN;
    const size_t bm = (size_t)(wg / gx) * BM;
    const size_t bn = (size_t)(wg % gx) * BN;

    f32x4 acc[8][2] = {};

    const int rho  = tid >> 3;
    const int slot = (((tid & 7) << 4) ^ (((tid >> 3) & 7) << 4));
    const f16* pA = A  + (bm + rho) * (size_t)K   + (slot >> 1);
    const f16* pB = Bt + (bn + rho) * (size_t)ldb + (slot >> 1);

    auto stA = [&](int b, int q, int T) {
        gload_lds16(pA + ((size_t)q * 64) * K + (size_t)T * BK,
                    (char*)sAc + b * AT + q * 8192 + wid * 1024);
    };
    auto stB = [&](int b, int q, int T) {
        gload_lds16(pB + ((size_t)q * 64) * ldb + (size_t)T * BK,
                    (char*)sBc + b * BT + q * 8192 + wid * 1024);
    };

    int offA0[8], offB0[2];
#pragma unroll
    for (int f = 0; f < 8; f++) {
        int r = wm * 128 + f * 16 + (lane & 15);
        offA0[f] = r * 128 + ((((lane >> 4) << 4)) ^ ((r & 7) << 4));
    }
#pragma unroll
    for (int f = 0; f < 2; f++) {
        int r = wn * 32 + f * 16 + (lane & 15);
        offB0[f] = r * 128 + ((((lane >> 4) << 4)) ^ ((r & 7) << 4));
    }

    f16x8 av[4], bv[2][2];

#define LDA4(B, MH, KC)                                                        \
    _Pragma("unroll") for (int f = 0; f < 4; f++)                              \
        av[f] = *(const f16x8*)(sAc + (B) * AT + (offA0[(MH)*4+f] ^ ((KC) << 6)));
#define LDBA(B)                                                                \
    _Pragma("unroll") for (int f = 0; f < 2; f++)                              \
    _Pragma("unroll") for (int kc = 0; kc < 2; kc++)                           \
        bv[f][kc] = *(const f16x8*)(sBc + (B) * BT + (offB0[f] ^ (kc << 6)));
#define OCT(MH, KC)                                                            \
    __builtin_amdgcn_s_setprio(1);                                             \
    _Pragma("unroll") for (int f = 0; f < 4; f++)                              \
    _Pragma("unroll") for (int g = 0; g < 2; g++)                              \
        acc[(MH)*4+f][g] = __builtin_amdgcn_mfma_f32_16x16x32_f16(             \
            av[f], bv[g][KC], acc[(MH)*4+f][g], 0, 0, 0);                      \
    __builtin_amdgcn_s_setprio(0);

    const int NT = K / BK, NI = NT / 2;

    stA(0,0,0); stA(0,2,0); stB(0,0,0); stB(0,1,0); stA(0,1,0); stA(0,3,0);
    stA(1,0,1); stA(1,2,1); stB(1,0,1); stB(1,1,1);
    asm volatile("s_waitcnt vmcnt(4)");
    __builtin_amdgcn_s_barrier();
    asm volatile("" ::: "memory");

    for (int i = 0; i < NI - 1; ++i) {
        const int t = 2 * i;
        LDA4(0, 0, 0) LDBA(0)
        stA(1, 1, t + 1); stA(1, 3, t + 1);
        SYNC_HEAD
        OCT(0, 0)
        SYNC_TAIL
        LDA4(0, 0, 1)
        SYNC_HEAD
        OCT(0, 1)
        SYNC_TAIL
        LDA4(0, 1, 0)
        stA(0, 0, t + 2); stA(0, 2, t + 2);
        SYNC_HEAD
        OCT(1, 0)
        SYNC_TAIL
        LDA4(0, 1, 1)
        stB(0, 0, t + 2); stB(0, 1, t + 2);
        SYNC_HEAD
        OCT(1, 1)
        asm volatile("s_waitcnt vmcnt(4)");
        SYNC_TAIL
        LDA4(1, 0, 0) LDBA(1)
        stA(0, 1, t + 2); stA(0, 3, t + 2);
        SYNC_HEAD
        OCT(0, 0)
        SYNC_TAIL
        LDA4(1, 0, 1)
        SYNC_HEAD
        OCT(0, 1)
        SYNC_TAIL
        LDA4(1, 1, 0)
        stA(1, 0, t + 3); stA(1, 2, t + 3);
        SYNC_HEAD
        OCT(1, 0)
        SYNC_TAIL
        LDA4(1, 1, 1)
        stB(1, 0, t + 3); stB(1, 1, t + 3);
        SYNC_HEAD
        OCT(1, 1)
        asm volatile("s_waitcnt vmcnt(4)");
        SYNC_TAIL
    }
    {   // final iteration
        LDA4(0, 0, 0) LDBA(0)
        stA(1, 1, NT - 1); stA(1, 3, NT - 1);
        SYNC_HEAD
        OCT(0, 0)
        SYNC_TAIL
        LDA4(0, 0, 1)
        SYNC_HEAD
        OCT(0, 1)
        SYNC_TAIL
        LDA4(0, 1, 0)
        SYNC_HEAD
        OCT(1, 0)
        SYNC_TAIL
        LDA4(0, 1, 1)
        SYNC_HEAD
        OCT(1, 1)
        asm volatile("s_waitcnt vmcnt(0)");
        SYNC_TAIL
        LDA4(1, 0, 0) LDBA(1)
        SYNC_HEAD
        OCT(0, 0)
        SYNC_TAIL
        LDA4(1, 0, 1)
        SYNC_HEAD
        OCT(0, 1)
        SYNC_TAIL
        LDA4(1, 1, 0)
        SYNC_HEAD
        OCT(1, 0)
        SYNC_TAIL
        LDA4(1, 1, 1)
        SYNC_HEAD
        OCT(1, 1)
        SYNC_TAIL
    }
#undef LDA4
#undef LDBA
#undef OCT

    const size_t row0 = bm + (size_t)wm * 128;
    const int col0 = (int)bn + wn * 32;
    const int c0 = lane & 15, r0 = (lane >> 4) * 4;
#pragma unroll
    for (int fm = 0; fm < 8; fm++)
#pragma unroll
        for (int r = 0; r < 4; r++) {
            const size_t row = row0 + fm * 16 + r0 + r;
            if constexpr (GN == 0) {
                const float g = gate[row * NE];
#pragma unroll
                for (int n = 0; n < 2; n++) {
                    const size_t col = (size_t)col0 + n * 16 + c0;
                    float v = (acc[fm][n][r] + bias[col]) * g;
                    float* p = Cptr + row * (size_t)N + col;
                    *p = ACCUM ? (*p + v) : v;
                }
            } else {
                float gv[GN];
#pragma unroll
                for (int j = 0; j < GN; j++) gv[j] = gate[row * NE + e0 + j];
#pragma unroll
                for (int n = 0; n < 2; n++) {
                    const size_t col = (size_t)col0 + n * 16 + c0;
                    float bb = 0.f;
#pragma unroll
                    for (int j = 0; j < GN; j++)
                        bb = fmaf(gv[j], bias[(size_t)(e0 + j) * N + col], bb);
                    float v = acc[fm][n][r] + bb;
                    float* p = Cptr + row * (size_t)N + col;
                    *p = ACCUM ? (*p + v) : v;
                }
            }
        }
}

// --------- gating head: logits = gh@gw2 + gb2, softmax -> gates fp32 -------
__global__ __launch_bounds__(256) void gate_softmax_kernel(
    const f16* __restrict__ gh, const float* __restrict__ gw2,
    const float* __restrict__ gb2, float* __restrict__ gates)
{
    const int row  = blockIdx.x * 4 + (threadIdx.x >> 6);
    const int lane = threadIdx.x & 63;
    const f16* r = gh + (size_t)row * HGD;
    float acc[NE] = {};
    for (int kb = lane * 8; kb < HGD; kb += 512) {
        f16x8 v = *(const f16x8*)(r + kb);
#pragma unroll
        for (int j = 0; j < 8; j++) {
            float h = (float)v[j];
            const float* w = gw2 + (size_t)(kb + j) * NE;
#pragma unroll
            for (int e = 0; e < NE; e++) acc[e] = fmaf(h, w[e], acc[e]);
        }
    }
#pragma unroll
    for (int off = 32; off > 0; off >>= 1)
#pragma unroll
        for (int e = 0; e < NE; e++) acc[e] += __shfl_down(acc[e], off, 64);
    if (lane == 0) {
        float l[NE], m = -1e30f;
#pragma unroll
        for (int e = 0; e < NE; e++) { l[e] = acc[e] + gb2[e]; m = fmaxf(m, l[e]); }
        float s = 0.f;
#pragma unroll
        for (int e = 0; e < NE; e++) { l[e] = expf(l[e] - m); s += l[e]; }
        float inv = 1.0f / s;
#pragma unroll
        for (int e = 0; e < NE; e++) gates[(size_t)row * NE + e] = l[e] * inv;
    }
}

// ---------------------------------------------------------------------------
extern "C" void kernel_launch(void* const* d_in, const int* in_sizes, int n_in,
                              void* d_out, int out_size, void* d_ws, size_t ws_size,
                              hipStream_t stream)
{
    const float* x   = (const float*)d_in[0];
    const float* gw1 = (const float*)d_in[1];
    const float* gb1 = (const float*)d_in[2];
    const float* gw2 = (const float*)d_in[3];
    const float* gb2 = (const float*)d_in[4];
    const float* ew1 = (const float*)d_in[5];
    const float* eb1 = (const float*)d_in[6];
    const float* ew2 = (const float*)d_in[7];
    const float* eb2 = (const float*)d_in[8];
    float* out = (float*)d_out;

    const size_t SZ_GATES = 256 << 10;
    const size_t SZ_X16   = (size_t)BSZ * IND * 2;       // 16 MB
    const size_t SZ_WBUF  = (size_t)HID * IND * 2;       //  8 MB
    const size_t SZ_W1ALL = (size_t)NE * HID * IND * 2;  // 64 MB
    const size_t SZ_W2ALL = (size_t)NE * OUTD * HID * 2; // 64 MB
    const size_t SZ_HB1   = (size_t)BSZ * HID * 2;       // 64 MB per expert
    const size_t BASE     = SZ_GATES + SZ_X16 + SZ_W1ALL + SZ_W2ALL;
    const size_t NEED_G4  = BASE + 4 * SZ_HB1;           // ~400 MB
    const size_t NEED_G2  = BASE + 2 * SZ_HB1;           // ~272 MB
    const size_t NEED_G1  = BASE + 1 * SZ_HB1;           // ~208 MB (r10 A)
    const size_t NEED_C   = SZ_GATES + SZ_X16 + SZ_WBUF + SZ_HB1;

    char* p = (char*)d_ws;
    float* gates = (float*)p;  p += SZ_GATES;
    f16* x16 = (f16*)p;        p += SZ_X16;

    conv_f32_f16_kernel<<<(BSZ * IND) / (256 * 8), 256, 0, stream>>>(x, x16);

    if (ws_size >= NEED_G2) {
        const int G = (ws_size >= NEED_G4) ? 4 : 2;
        f16* w1all = (f16*)p;  p += SZ_W1ALL;
        f16* w2cat = (f16*)p;  p += SZ_W2ALL;
        f16* hbufG = (f16*)p;                   // G * 64 MB
        f16* gh    = hbufG;                     // 32 MB alias, consumed early

        // gating: gw1^T into w1all scratch (overwritten later)
        transpose_f32_f16_kernel<<<dim3(HGD / 64, IND / 64, 1), 256, 0, stream>>>(
            gw1, w1all, IND, HGD, IND, 0, 0);
        gemm256_kernel<true, false>
            <<<dim3((HGD / 256) * (BSZ / 256), 1, 1), 512, 0, stream>>>(
                x16, w1all, gb1, nullptr, gh, BSZ, HGD, IND, HGD, 0);
        gate_softmax_kernel<<<BSZ / 4, 256, 0, stream>>>(gh, gw2, gb2, gates);

        // batched transposes: w1all[e][HID][IND]; w2cat[o][e*HID+h]
        transpose_f32_f16_kernel<<<dim3(HID / 64, IND / 64, NE), 256, 0, stream>>>(
            ew1, w1all, IND, HID, IND, (size_t)HID * IND, 0);
        transpose_f32_f16_kernel<<<dim3(OUTD / 64, HID / 64, NE), 256, 0, stream>>>(
            ew2, w2cat, HID, OUTD, NE * HID, 0, HID);

        for (int g = 0; g < NE / G; g++) {
            // hs[:, z*HID:(z+1)*HID] = gate_{gG+z} * relu(x@w1 + b1), z<G
            gemm256_kernel<true, true>
                <<<dim3((HID / 256) * (BSZ / 256), 1, G), 512, 0, stream>>>(
                    x16, w1all + (size_t)g * G * HID * IND, eb1 + g * G * HID,
                    gates, hbufG, BSZ, HID, IND, G * HID, g * G);
            // out (+)= hs @ w2cat[:, gG*HID:(g+1)G*HID] + sum_j gate_j*eb2_j
            if (G == 4) {
                if (g == 0)
                    gemmO_kernel<false, 4>
                        <<<(OUTD / 128) * (BSZ / 256), 512, 0, stream>>>(
                            hbufG, w2cat + (size_t)g * G * HID, eb2, gates, out,
                            BSZ, OUTD, G * HID, NE * HID, g * G);
                else
                    gemmO_kernel<true, 4>
                        <<<(OUTD / 128) * (BSZ / 256), 512, 0, stream>>>(
                            hbufG, w2cat + (size_t)g * G * HID, eb2, gates, out,
                            BSZ, OUTD, G * HID, NE * HID, g * G);
            } else {
                if (g == 0)
                    gemmO_kernel<false, 2>
                        <<<(OUTD / 128) * (BSZ / 256), 512, 0, stream>>>(
                            hbufG, w2cat + (size_t)g * G * HID, eb2, gates, out,
                            BSZ, OUTD, G * HID, NE * HID, g * G);
                else
                    gemmO_kernel<true, 2>
                        <<<(OUTD / 128) * (BSZ / 256), 512, 0, stream>>>(
                            hbufG, w2cat + (size_t)g * G * HID, eb2, gates, out,
                            BSZ, OUTD, G * HID, NE * HID, g * G);
            }
        }
    } else if (ws_size >= NEED_G1) {
        // ---- r10 tier A (verified): batched transposes, per-expert GEMMs ----
        f16* w1all = (f16*)p;  p += SZ_W1ALL;
        f16* w2all = (f16*)p;  p += SZ_W2ALL;
        f16* hbuf  = (f16*)p;
        f16* gh    = hbuf;

        transpose_f32_f16_kernel<<<dim3(HGD / 64, IND / 64, 1), 256, 0, stream>>>(
            gw1, w1all, IND, HGD, IND, 0, 0);
        gemm256_kernel<true, false>
            <<<dim3((HGD / 256) * (BSZ / 256), 1, 1), 512, 0, stream>>>(
                x16, w1all, gb1, nullptr, gh, BSZ, HGD, IND, HGD, 0);
        gate_softmax_kernel<<<BSZ / 4, 256, 0, stream>>>(gh, gw2, gb2, gates);

        transpose_f32_f16_kernel<<<dim3(HID / 64, IND / 64, NE), 256, 0, stream>>>(
            ew1, w1all, IND, HID, IND, (size_t)HID * IND, 0);
        transpose_f32_f16_kernel<<<dim3(OUTD / 64, HID / 64, NE), 256, 0, stream>>>(
            ew2, w2all, HID, OUTD, HID, (size_t)OUTD * HID, 0);

        for (int e = 0; e < NE; e++) {
            gemm256_kernel<true, false>
                <<<dim3((HID / 256) * (BSZ / 256), 1, 1), 512, 0, stream>>>(
                    x16, w1all + (size_t)e * HID * IND, eb1 + (size_t)e * HID,
                    nullptr, hbuf, BSZ, HID, IND, HID, 0);
            if (e == 0)
                gemmO_kernel<false, 0><<<(OUTD / 128) * (BSZ / 256), 512, 0, stream>>>(
                    hbuf, w2all + (size_t)e * OUTD * HID, eb2 + (size_t)e * OUTD,
                    gates + e, out, BSZ, OUTD, HID, HID, 0);
            else
                gemmO_kernel<true, 0><<<(OUTD / 128) * (BSZ / 256), 512, 0, stream>>>(
                    hbuf, w2all + (size_t)e * OUTD * HID, eb2 + (size_t)e * OUTD,
                    gates + e, out, BSZ, OUTD, HID, HID, 0);
        }
    } else {
        // ---- tier C: exact r4 fallback ----
        f16* wbuf = (f16*)p;   p += SZ_WBUF;
        f16* hbuf = (f16*)p;
        f16* gh   = hbuf;

        transpose_f32_f16_kernel<<<dim3(HGD / 64, IND / 64, 1), 256, 0, stream>>>(
            gw1, wbuf, IND, HGD, IND, 0, 0);
        gemm256_kernel<true, false>
            <<<dim3((HGD / 256) * (BSZ / 256), 1, 1), 512, 0, stream>>>(
                x16, wbuf, gb1, nullptr, gh, BSZ, HGD, IND, HGD, 0);
        gate_softmax_kernel<<<BSZ / 4, 256, 0, stream>>>(gh, gw2, gb2, gates);

        for (int e = 0; e < NE; e++) {
            transpose_f32_f16_kernel<<<dim3(HID / 64, IND / 64, 1), 256, 0, stream>>>(
                ew1 + (size_t)e * IND * HID, wbuf, IND, HID, IND, 0, 0);
            gemm256_kernel<true, false>
                <<<dim3((HID / 256) * (BSZ / 256), 1, 1), 512, 0, stream>>>(
                    x16, wbuf, eb1 + (size_t)e * HID, nullptr, hbuf,
                    BSZ, HID, IND, HID, 0);

            transpose_f32_f16_kernel<<<dim3(OUTD / 64, HID / 64, 1), 256, 0, stream>>>(
                ew2 + (size_t)e * HID * OUTD, wbuf, HID, OUTD, HID, 0, 0);
            if (e == 0)
                gemmO_kernel<false, 0><<<(OUTD / 128) * (BSZ / 256), 512, 0, stream>>>(
                    hbuf, wbuf, eb2 + (size_t)e * OUTD, gates + e, out,
                    BSZ, OUTD, HID, HID, 0);
            else
                gemmO_kernel<true, 0><<<(OUTD / 128) * (BSZ / 256), 512, 0, stream>>>(
                    hbuf, wbuf, eb2 + (size_t)e * OUTD, gates + e, out,
                    BSZ, OUTD, HID, HID, 0);
        }
    }
}

// Round 12
// 1316.020 us; speedup vs baseline: 12.4863x; 1.0023x over previous
//
#include <hip/hip_runtime.h>

// ---------------------------------------------------------------------------
// MoE forward: gating MLP + 8 dense experts + gate-weighted combine.
// r12 = r11 (grouped G=4 fusion, gate folded into hs, bias-dot OUT epilogue)
// with the lgkmcnt(0) walls + read-side sched_barrier(0) pins REMOVED from
// the GEMM phase sync (m97: compiler emits fine-grained lgkmcnt itself;
// m141: order-pinning regresses). Phase head = bare s_barrier; tail keeps
// counted vmcnt + sched_barrier + s_barrier + memory clobber (WAR safety:
// each phase's reads are consumed by its own MFMAs -> complete before the
// trailing barrier; overwrites land >=2 barriers later per FIFO design).
// ---------------------------------------------------------------------------

#define DI __device__ __forceinline__

typedef _Float16 f16;
typedef _Float16 f16x8 __attribute__((ext_vector_type(8)));
typedef float f32x4 __attribute__((ext_vector_type(4)));

constexpr int BSZ  = 8192;
constexpr int IND  = 1024;
constexpr int HID  = 4096;
constexpr int OUTD = 1024;
constexpr int NE   = 8;
constexpr int HGD  = 2048;

// ---------------- fp32 -> fp16 vectorized convert (8 elems/thread) ---------
__global__ __launch_bounds__(256) void conv_f32_f16_kernel(
    const float* __restrict__ in, f16* __restrict__ out)
{
    size_t i = ((size_t)blockIdx.x * 256 + threadIdx.x) * 8;
    const float4* p = (const float4*)(in + i);
    float4 a = p[0], b = p[1];
    f16x8 v = {(f16)a.x, (f16)a.y, (f16)a.z, (f16)a.w,
               (f16)b.x, (f16)b.y, (f16)b.z, (f16)b.w};
    *(f16x8*)(out + i) = v;
}

// transpose+convert: W[z][K][N] f32 -> Wt[z*zstride + n*ldo + z*kostep + k]
__global__ __launch_bounds__(256) void transpose_f32_f16_kernel(
    const float* __restrict__ W, f16* __restrict__ Wt, int K, int N,
    int ldo, size_t zstride, int kostep)
{
    const int z = blockIdx.z;
    W += (size_t)z * K * N;
    f16* base = Wt + (size_t)z * zstride + (size_t)z * kostep;
    __shared__ float t[64][65];
    int n0 = blockIdx.x * 64, k0 = blockIdx.y * 64;
    int tx = threadIdx.x & 63, ty = threadIdx.x >> 6;
#pragma unroll
    for (int i = 0; i < 16; i++) {
        int k = i * 4 + ty;
        t[k][tx] = W[(size_t)(k0 + k) * N + n0 + tx];
    }
    __syncthreads();
#pragma unroll
    for (int i = 0; i < 16; i++) {
        int n = i * 4 + ty;
        base[(size_t)(n0 + n) * ldo + k0 + tx] = (f16)t[tx][n];
    }
}

// ---------------- async global->LDS (16B per lane, wave-uniform dest) ------
DI void gload_lds16(const void* g, void* l)
{
    typedef const __attribute__((address_space(1))) unsigned int as1_t;
    typedef __attribute__((address_space(3))) unsigned int as3_t;
    __builtin_amdgcn_global_load_lds(
        (as1_t*)(unsigned long long)(__SIZE_TYPE__)g,
        (as3_t*)(unsigned int)(__SIZE_TYPE__)l,
        16, 0, 0);
}

// phase sync: head = bare barrier (compiler schedules its own lgkm waits);
// tail = [counted vmcnt before] sched_barrier + barrier + memory clobber.
#define SYNC_HEAD    __builtin_amdgcn_s_barrier();
#define SYNC_HEAD_T8 __builtin_amdgcn_s_barrier();
#define SYNC_TAIL                                                              \
    __builtin_amdgcn_sched_barrier(0);                                         \
    __builtin_amdgcn_s_barrier();                                              \
    asm volatile("" ::: "memory");

// ---------------------------------------------------------------------------
// gemm256: BM=256, BN=256, BK=64, 8 waves 2Mx4N. blockIdx.z = sub-expert:
// Bt += z*N*K, bias += z*N, C col base z*N. GSCALE: v = relu(v)*gate[..e0+z].
// ---------------------------------------------------------------------------
template <bool RELU, bool GSCALE>
__global__ __launch_bounds__(512, 2) void gemm256_kernel(
    const f16* __restrict__ A, const f16* __restrict__ Bt,
    const float* __restrict__ bias, const float* __restrict__ gate,
    f16* __restrict__ Cptr, int M, int N, int K, int ldc, int e0)
{
    constexpr int BM = 256, BN = 256, BK = 64;
    constexpr int AT = BM * BK * 2, BT = BN * BK * 2;
    __shared__ __align__(16) f16 sA[2][BM * BK];
    __shared__ __align__(16) f16 sB[2][BN * BK];
    const char* sAc = (const char*)sA;
    const char* sBc = (const char*)sB;

    const int z = blockIdx.z;
    Bt   += (size_t)z * N * K;
    bias += (size_t)z * N;

    const int tid = threadIdx.x, wid = tid >> 6, lane = tid & 63;
    const int wm = wid >> 2, wn = wid & 3;
    const int nwg = gridDim.x, bid = blockIdx.x;
    const int wg = (bid & 7) * (nwg >> 3) + (bid >> 3);
    const int gx = N / BN;
    const size_t bm = (size_t)(wg / gx) * BM;
    const size_t bn = (size_t)(wg % gx) * BN;

    f32x4 acc[8][4] = {};

    const int rho  = tid >> 3;
    const int slot = (((tid & 7) << 4) ^ (((tid >> 3) & 7) << 4));
    const f16* pA = A  + (bm + rho) * (size_t)K + (slot >> 1);
    const f16* pB = Bt + (bn + rho) * (size_t)K + (slot >> 1);

    auto stA = [&](int b, int q, int T) {
        gload_lds16(pA + ((size_t)q * 64) * K + (size_t)T * BK,
                    (char*)sAc + b * AT + q * 8192 + wid * 1024);
    };
    auto stB = [&](int b, int q, int T) {
        gload_lds16(pB + ((size_t)q * 64) * K + (size_t)T * BK,
                    (char*)sBc + b * BT + q * 8192 + wid * 1024);
    };

    int offA0[8], offB0[4];
#pragma unroll
    for (int f = 0; f < 8; f++) {
        int r = wm * 128 + f * 16 + (lane & 15);
        offA0[f] = r * 128 + ((((lane >> 4) << 4)) ^ ((r & 7) << 4));
    }
#pragma unroll
    for (int f = 0; f < 4; f++) {
        int r = wn * 64 + f * 16 + (lane & 15);
        offB0[f] = r * 128 + ((((lane >> 4) << 4)) ^ ((r & 7) << 4));
    }

    f16x8 av[4][2], bv0[2][2], bv1[2][2];

#define LDAQ(B, MH)                                                            \
    _Pragma("unroll") for (int f = 0; f < 4; f++)                              \
    _Pragma("unroll") for (int kc = 0; kc < 2; kc++)                           \
        av[f][kc] = *(const f16x8*)(sAc + (B) * AT + (offA0[(MH)*4+f] ^ (kc << 6)));
#define LDBH(B, NH, BV)                                                        \
    _Pragma("unroll") for (int f = 0; f < 2; f++)                              \
    _Pragma("unroll") for (int kc = 0; kc < 2; kc++)                           \
        BV[f][kc] = *(const f16x8*)(sBc + (B) * BT + (offB0[(NH)*2+f] ^ (kc << 6)));
#define QUAD(MH, NH, BV)                                                       \
    __builtin_amdgcn_s_setprio(1);                                             \
    _Pragma("unroll") for (int f = 0; f < 4; f++)                              \
    _Pragma("unroll") for (int g = 0; g < 2; g++)                              \
    _Pragma("unroll") for (int kc = 0; kc < 2; kc++)                           \
        acc[(MH)*4+f][(NH)*2+g] = __builtin_amdgcn_mfma_f32_16x16x32_f16(      \
            av[f][kc], BV[g][kc], acc[(MH)*4+f][(NH)*2+g], 0, 0, 0);           \
    __builtin_amdgcn_s_setprio(0);

    const int NT = K / BK, NI = NT / 2;

    stA(0,0,0); stA(0,2,0); stB(0,0,0); stB(0,1,0); stB(0,2,0); stB(0,3,0);
    stA(0,1,0); stA(0,3,0);
    stA(1,0,1); stA(1,2,1); stB(1,0,1); stB(1,1,1); stB(1,2,1); stB(1,3,1);
    asm volatile("s_waitcnt vmcnt(6)");
    __builtin_amdgcn_s_barrier();
    asm volatile("" ::: "memory");

    for (int i = 0; i < NI - 1; ++i) {
        const int t = 2 * i;
        LDAQ(0, 0) LDBH(0, 0, bv0)
        stA(1, 1, t + 1); stA(1, 3, t + 1);
        SYNC_HEAD_T8
        QUAD(0, 0, bv0)
        SYNC_TAIL
        LDBH(0, 1, bv1)
        stA(0, 0, t + 2); stA(0, 2, t + 2);
        SYNC_HEAD
        QUAD(0, 1, bv1)
        SYNC_TAIL
        LDAQ(0, 1)
        stB(0, 0, t + 2); stB(0, 1, t + 2);
        SYNC_HEAD
        QUAD(1, 1, bv1)
        SYNC_TAIL
        stB(0, 2, t + 2); stB(0, 3, t + 2);
        SYNC_HEAD
        QUAD(1, 0, bv0)
        asm volatile("s_waitcnt vmcnt(6)");
        SYNC_TAIL
        LDAQ(1, 0) LDBH(1, 0, bv0)
        stA(0, 1, t + 2); stA(0, 3, t + 2);
        SYNC_HEAD_T8
        QUAD(0, 0, bv0)
        SYNC_TAIL
        LDBH(1, 1, bv1)
        stA(1, 0, t + 3); stA(1, 2, t + 3);
        SYNC_HEAD
        QUAD(0, 1, bv1)
        SYNC_TAIL
        LDAQ(1, 1)
        stB(1, 0, t + 3); stB(1, 1, t + 3);
        SYNC_HEAD
        QUAD(1, 1, bv1)
        SYNC_TAIL
        stB(1, 2, t + 3); stB(1, 3, t + 3);
        SYNC_HEAD
        QUAD(1, 0, bv0)
        asm volatile("s_waitcnt vmcnt(6)");
        SYNC_TAIL
    }
    {   // final iteration (tiles NT-2, NT-1)
        LDAQ(0, 0) LDBH(0, 0, bv0)
        stA(1, 1, NT - 1); stA(1, 3, NT - 1);
        SYNC_HEAD_T8
        QUAD(0, 0, bv0)
        SYNC_TAIL
        LDBH(0, 1, bv1)
        SYNC_HEAD
        QUAD(0, 1, bv1)
        SYNC_TAIL
        LDAQ(0, 1)
        SYNC_HEAD
        QUAD(1, 1, bv1)
        SYNC_TAIL
        SYNC_HEAD
        QUAD(1, 0, bv0)
        asm volatile("s_waitcnt vmcnt(0)");
        SYNC_TAIL
        LDAQ(1, 0) LDBH(1, 0, bv0)
        SYNC_HEAD
        QUAD(0, 0, bv0)
        SYNC_TAIL
        LDBH(1, 1, bv1)
        SYNC_HEAD
        QUAD(0, 1, bv1)
        SYNC_TAIL
        LDAQ(1, 1)
        SYNC_HEAD
        QUAD(1, 1, bv1)
        SYNC_TAIL
        SYNC_HEAD
        QUAD(1, 0, bv0)
        SYNC_TAIL
    }
#undef LDAQ
#undef LDBH
#undef QUAD

    const size_t row0 = bm + (size_t)wm * 128;
    const int col0 = (int)bn + wn * 64;
    const int c0 = lane & 15, r0 = (lane >> 4) * 4;
    f16* Cz = Cptr + (size_t)z * N;
#pragma unroll
    for (int fm = 0; fm < 8; fm++)
#pragma unroll
        for (int r = 0; r < 4; r++) {
            const size_t row = row0 + fm * 16 + r0 + r;
            float g = 1.0f;
            if constexpr (GSCALE) g = gate[row * NE + e0 + z];
#pragma unroll
            for (int n = 0; n < 4; n++) {
                const size_t col = (size_t)col0 + n * 16 + c0;
                float v = acc[fm][n][r] + bias[col];
                if constexpr (RELU) v = fmaxf(v, 0.0f);
                if constexpr (GSCALE) v *= g;
                Cz[row * (size_t)ldc + col] = (f16)v;
            }
        }
}

// ---------------------------------------------------------------------------
// gemmO: BM=256, BN=128, BK=64, 8 waves 2Mx4N. B row stride = ldb.
// GN==0: (acc+bias[col])*gate[row*NE]. GN>0: acc + sum_j gate_j*bias_j[col].
// ---------------------------------------------------------------------------
template <bool ACCUM, int GN>
__global__ __launch_bounds__(512, 2) void gemmO_kernel(
    const f16* __restrict__ A, const f16* __restrict__ Bt,
    const float* __restrict__ bias, const float* __restrict__ gate,
    float* __restrict__ Cptr, int M, int N, int K, int ldb, int e0)
{
    constexpr int BM = 256, BN = 128, BK = 64;
    constexpr int AT = BM * BK * 2, BT = BN * BK * 2;
    __shared__ __align__(16) f16 sA[2][BM * BK];
    __shared__ __align__(16) f16 sB[2][BN * BK];
    const char* sAc = (const char*)sA;
    const char* sBc = (const char*)sB;

    const int tid = threadIdx.x, wid = tid >> 6, lane = tid & 63;
    const int wm = wid >> 2, wn = wid & 3;
    const int nwg = gridDim.x, bid = blockIdx.x;
    const int wg = (bid & 7) * (nwg >> 3) + (bid >> 3);
    const int gx = N / BN;
    const size_t bm = (size_t)(wg / gx) * BM;
    const size_t bn = (size_t)(wg % gx) * BN;

    f32x4 acc[8][2] = {};

    const int rho  = tid >> 3;
    const int slot = (((tid & 7) << 4) ^ (((tid >> 3) & 7) << 4));
    const f16* pA = A  + (bm + rho) * (size_t)K   + (slot >> 1);
    const f16* pB = Bt + (bn + rho) * (size_t)ldb + (slot >> 1);

    auto stA = [&](int b, int q, int T) {
        gload_lds16(pA + ((size_t)q * 64) * K + (size_t)T * BK,
                    (char*)sAc + b * AT + q * 8192 + wid * 1024);
    };
    auto stB = [&](int b, int q, int T) {
        gload_lds16(pB + ((size_t)q * 64) * ldb + (size_t)T * BK,
                    (char*)sBc + b * BT + q * 8192 + wid * 1024);
    };

    int offA0[8], offB0[2];
#pragma unroll
    for (int f = 0; f < 8; f++) {
        int r = wm * 128 + f * 16 + (lane & 15);
        offA0[f] = r * 128 + ((((lane >> 4) << 4)) ^ ((r & 7) << 4));
    }
#pragma unroll
    for (int f = 0; f < 2; f++) {
        int r = wn * 32 + f * 16 + (lane & 15);
        offB0[f] = r * 128 + ((((lane >> 4) << 4)) ^ ((r & 7) << 4));
    }

    f16x8 av[4], bv[2][2];

#define LDA4(B, MH, KC)                                                        \
    _Pragma("unroll") for (int f = 0; f < 4; f++)                              \
        av[f] = *(const f16x8*)(sAc + (B) * AT + (offA0[(MH)*4+f] ^ ((KC) << 6)));
#define LDBA(B)                                                                \
    _Pragma("unroll") for (int f = 0; f < 2; f++)                              \
    _Pragma("unroll") for (int kc = 0; kc < 2; kc++)                           \
        bv[f][kc] = *(const f16x8*)(sBc + (B) * BT + (offB0[f] ^ (kc << 6)));
#define OCT(MH, KC)                                                            \
    __builtin_amdgcn_s_setprio(1);                                             \
    _Pragma("unroll") for (int f = 0; f < 4; f++)                              \
    _Pragma("unroll") for (int g = 0; g < 2; g++)                              \
        acc[(MH)*4+f][g] = __builtin_amdgcn_mfma_f32_16x16x32_f16(             \
            av[f], bv[g][KC], acc[(MH)*4+f][g], 0, 0, 0);                      \
    __builtin_amdgcn_s_setprio(0);

    const int NT = K / BK, NI = NT / 2;

    stA(0,0,0); stA(0,2,0); stB(0,0,0); stB(0,1,0); stA(0,1,0); stA(0,3,0);
    stA(1,0,1); stA(1,2,1); stB(1,0,1); stB(1,1,1);
    asm volatile("s_waitcnt vmcnt(4)");
    __builtin_amdgcn_s_barrier();
    asm volatile("" ::: "memory");

    for (int i = 0; i < NI - 1; ++i) {
        const int t = 2 * i;
        LDA4(0, 0, 0) LDBA(0)
        stA(1, 1, t + 1); stA(1, 3, t + 1);
        SYNC_HEAD
        OCT(0, 0)
        SYNC_TAIL
        LDA4(0, 0, 1)
        SYNC_HEAD
        OCT(0, 1)
        SYNC_TAIL
        LDA4(0, 1, 0)
        stA(0, 0, t + 2); stA(0, 2, t + 2);
        SYNC_HEAD
        OCT(1, 0)
        SYNC_TAIL
        LDA4(0, 1, 1)
        stB(0, 0, t + 2); stB(0, 1, t + 2);
        SYNC_HEAD
        OCT(1, 1)
        asm volatile("s_waitcnt vmcnt(4)");
        SYNC_TAIL
        LDA4(1, 0, 0) LDBA(1)
        stA(0, 1, t + 2); stA(0, 3, t + 2);
        SYNC_HEAD
        OCT(0, 0)
        SYNC_TAIL
        LDA4(1, 0, 1)
        SYNC_HEAD
        OCT(0, 1)
        SYNC_TAIL
        LDA4(1, 1, 0)
        stA(1, 0, t + 3); stA(1, 2, t + 3);
        SYNC_HEAD
        OCT(1, 0)
        SYNC_TAIL
        LDA4(1, 1, 1)
        stB(1, 0, t + 3); stB(1, 1, t + 3);
        SYNC_HEAD
        OCT(1, 1)
        asm volatile("s_waitcnt vmcnt(4)");
        SYNC_TAIL
    }
    {   // final iteration
        LDA4(0, 0, 0) LDBA(0)
        stA(1, 1, NT - 1); stA(1, 3, NT - 1);
        SYNC_HEAD
        OCT(0, 0)
        SYNC_TAIL
        LDA4(0, 0, 1)
        SYNC_HEAD
        OCT(0, 1)
        SYNC_TAIL
        LDA4(0, 1, 0)
        SYNC_HEAD
        OCT(1, 0)
        SYNC_TAIL
        LDA4(0, 1, 1)
        SYNC_HEAD
        OCT(1, 1)
        asm volatile("s_waitcnt vmcnt(0)");
        SYNC_TAIL
        LDA4(1, 0, 0) LDBA(1)
        SYNC_HEAD
        OCT(0, 0)
        SYNC_TAIL
        LDA4(1, 0, 1)
        SYNC_HEAD
        OCT(0, 1)
        SYNC_TAIL
        LDA4(1, 1, 0)
        SYNC_HEAD
        OCT(1, 0)
        SYNC_TAIL
        LDA4(1, 1, 1)
        SYNC_HEAD
        OCT(1, 1)
        SYNC_TAIL
    }
#undef LDA4
#undef LDBA
#undef OCT

    const size_t row0 = bm + (size_t)wm * 128;
    const int col0 = (int)bn + wn * 32;
    const int c0 = lane & 15, r0 = (lane >> 4) * 4;
#pragma unroll
    for (int fm = 0; fm < 8; fm++)
#pragma unroll
        for (int r = 0; r < 4; r++) {
            const size_t row = row0 + fm * 16 + r0 + r;
            if constexpr (GN == 0) {
                const float g = gate[row * NE];
#pragma unroll
                for (int n = 0; n < 2; n++) {
                    const size_t col = (size_t)col0 + n * 16 + c0;
                    float v = (acc[fm][n][r] + bias[col]) * g;
                    float* p = Cptr + row * (size_t)N + col;
                    *p = ACCUM ? (*p + v) : v;
                }
            } else {
                float gv[GN];
#pragma unroll
                for (int j = 0; j < GN; j++) gv[j] = gate[row * NE + e0 + j];
#pragma unroll
                for (int n = 0; n < 2; n++) {
                    const size_t col = (size_t)col0 + n * 16 + c0;
                    float bb = 0.f;
#pragma unroll
                    for (int j = 0; j < GN; j++)
                        bb = fmaf(gv[j], bias[(size_t)(e0 + j) * N + col], bb);
                    float v = acc[fm][n][r] + bb;
                    float* p = Cptr + row * (size_t)N + col;
                    *p = ACCUM ? (*p + v) : v;
                }
            }
        }
}

// --------- gating head: logits = gh@gw2 + gb2, softmax -> gates fp32 -------
__global__ __launch_bounds__(256) void gate_softmax_kernel(
    const f16* __restrict__ gh, const float* __restrict__ gw2,
    const float* __restrict__ gb2, float* __restrict__ gates)
{
    const int row  = blockIdx.x * 4 + (threadIdx.x >> 6);
    const int lane = threadIdx.x & 63;
    const f16* r = gh + (size_t)row * HGD;
    float acc[NE] = {};
    for (int kb = lane * 8; kb < HGD; kb += 512) {
        f16x8 v = *(const f16x8*)(r + kb);
#pragma unroll
        for (int j = 0; j < 8; j++) {
            float h = (float)v[j];
            const float* w = gw2 + (size_t)(kb + j) * NE;
#pragma unroll
            for (int e = 0; e < NE; e++) acc[e] = fmaf(h, w[e], acc[e]);
        }
    }
#pragma unroll
    for (int off = 32; off > 0; off >>= 1)
#pragma unroll
        for (int e = 0; e < NE; e++) acc[e] += __shfl_down(acc[e], off, 64);
    if (lane == 0) {
        float l[NE], m = -1e30f;
#pragma unroll
        for (int e = 0; e < NE; e++) { l[e] = acc[e] + gb2[e]; m = fmaxf(m, l[e]); }
        float s = 0.f;
#pragma unroll
        for (int e = 0; e < NE; e++) { l[e] = expf(l[e] - m); s += l[e]; }
        float inv = 1.0f / s;
#pragma unroll
        for (int e = 0; e < NE; e++) gates[(size_t)row * NE + e] = l[e] * inv;
    }
}

// ---------------------------------------------------------------------------
extern "C" void kernel_launch(void* const* d_in, const int* in_sizes, int n_in,
                              void* d_out, int out_size, void* d_ws, size_t ws_size,
                              hipStream_t stream)
{
    const float* x   = (const float*)d_in[0];
    const float* gw1 = (const float*)d_in[1];
    const float* gb1 = (const float*)d_in[2];
    const float* gw2 = (const float*)d_in[3];
    const float* gb2 = (const float*)d_in[4];
    const float* ew1 = (const float*)d_in[5];
    const float* eb1 = (const float*)d_in[6];
    const float* ew2 = (const float*)d_in[7];
    const float* eb2 = (const float*)d_in[8];
    float* out = (float*)d_out;

    const size_t SZ_GATES = 256 << 10;
    const size_t SZ_X16   = (size_t)BSZ * IND * 2;
    const size_t SZ_WBUF  = (size_t)HID * IND * 2;
    const size_t SZ_W1ALL = (size_t)NE * HID * IND * 2;
    const size_t SZ_W2ALL = (size_t)NE * OUTD * HID * 2;
    const size_t SZ_HB1   = (size_t)BSZ * HID * 2;
    const size_t BASE     = SZ_GATES + SZ_X16 + SZ_W1ALL + SZ_W2ALL;
    const size_t NEED_G4  = BASE + 4 * SZ_HB1;
    const size_t NEED_G2  = BASE + 2 * SZ_HB1;
    const size_t NEED_G1  = BASE + 1 * SZ_HB1;

    char* p = (char*)d_ws;
    float* gates = (float*)p;  p += SZ_GATES;
    f16* x16 = (f16*)p;        p += SZ_X16;

    conv_f32_f16_kernel<<<(BSZ * IND) / (256 * 8), 256, 0, stream>>>(x, x16);

    if (ws_size >= NEED_G2) {
        const int G = (ws_size >= NEED_G4) ? 4 : 2;
        f16* w1all = (f16*)p;  p += SZ_W1ALL;
        f16* w2cat = (f16*)p;  p += SZ_W2ALL;
        f16* hbufG = (f16*)p;
        f16* gh    = hbufG;

        transpose_f32_f16_kernel<<<dim3(HGD / 64, IND / 64, 1), 256, 0, stream>>>(
            gw1, w1all, IND, HGD, IND, 0, 0);
        gemm256_kernel<true, false>
            <<<dim3((HGD / 256) * (BSZ / 256), 1, 1), 512, 0, stream>>>(
                x16, w1all, gb1, nullptr, gh, BSZ, HGD, IND, HGD, 0);
        gate_softmax_kernel<<<BSZ / 4, 256, 0, stream>>>(gh, gw2, gb2, gates);

        transpose_f32_f16_kernel<<<dim3(HID / 64, IND / 64, NE), 256, 0, stream>>>(
            ew1, w1all, IND, HID, IND, (size_t)HID * IND, 0);
        transpose_f32_f16_kernel<<<dim3(OUTD / 64, HID / 64, NE), 256, 0, stream>>>(
            ew2, w2cat, HID, OUTD, NE * HID, 0, HID);

        for (int g = 0; g < NE / G; g++) {
            gemm256_kernel<true, true>
                <<<dim3((HID / 256) * (BSZ / 256), 1, G), 512, 0, stream>>>(
                    x16, w1all + (size_t)g * G * HID * IND, eb1 + g * G * HID,
                    gates, hbufG, BSZ, HID, IND, G * HID, g * G);
            if (G == 4) {
                if (g == 0)
                    gemmO_kernel<false, 4>
                        <<<(OUTD / 128) * (BSZ / 256), 512, 0, stream>>>(
                            hbufG, w2cat + (size_t)g * G * HID, eb2, gates, out,
                            BSZ, OUTD, G * HID, NE * HID, g * G);
                else
                    gemmO_kernel<true, 4>
                        <<<(OUTD / 128) * (BSZ / 256), 512, 0, stream>>>(
                            hbufG, w2cat + (size_t)g * G * HID, eb2, gates, out,
                            BSZ, OUTD, G * HID, NE * HID, g * G);
            } else {
                if (g == 0)
                    gemmO_kernel<false, 2>
                        <<<(OUTD / 128) * (BSZ / 256), 512, 0, stream>>>(
                            hbufG, w2cat + (size_t)g * G * HID, eb2, gates, out,
                            BSZ, OUTD, G * HID, NE * HID, g * G);
                else
                    gemmO_kernel<true, 2>
                        <<<(OUTD / 128) * (BSZ / 256), 512, 0, stream>>>(
                            hbufG, w2cat + (size_t)g * G * HID, eb2, gates, out,
                            BSZ, OUTD, G * HID, NE * HID, g * G);
            }
        }
    } else if (ws_size >= NEED_G1) {
        f16* w1all = (f16*)p;  p += SZ_W1ALL;
        f16* w2all = (f16*)p;  p += SZ_W2ALL;
        f16* hbuf  = (f16*)p;
        f16* gh    = hbuf;

        transpose_f32_f16_kernel<<<dim3(HGD / 64, IND / 64, 1), 256, 0, stream>>>(
            gw1, w1all, IND, HGD, IND, 0, 0);
        gemm256_kernel<true, false>
            <<<dim3((HGD / 256) * (BSZ / 256), 1, 1), 512, 0, stream>>>(
                x16, w1all, gb1, nullptr, gh, BSZ, HGD, IND, HGD, 0);
        gate_softmax_kernel<<<BSZ / 4, 256, 0, stream>>>(gh, gw2, gb2, gates);

        transpose_f32_f16_kernel<<<dim3(HID / 64, IND / 64, NE), 256, 0, stream>>>(
            ew1, w1all, IND, HID, IND, (size_t)HID * IND, 0);
        transpose_f32_f16_kernel<<<dim3(OUTD / 64, HID / 64, NE), 256, 0, stream>>>(
            ew2, w2all, HID, OUTD, HID, (size_t)OUTD * HID, 0);

        for (int e = 0; e < NE; e++) {
            gemm256_kernel<true, false>
                <<<dim3((HID / 256) * (BSZ / 256), 1, 1), 512, 0, stream>>>(
                    x16, w1all + (size_t)e * HID * IND, eb1 + (size_t)e * HID,
                    nullptr, hbuf, BSZ, HID, IND, HID, 0);
            if (e == 0)
                gemmO_kernel<false, 0><<<(OUTD / 128) * (BSZ / 256), 512, 0, stream>>>(
                    hbuf, w2all + (size_t)e * OUTD * HID, eb2 + (size_t)e * OUTD,
                    gates + e, out, BSZ, OUTD, HID, HID, 0);
            else
                gemmO_kernel<true, 0><<<(OUTD / 128) * (BSZ / 256), 512, 0, stream>>>(
                    hbuf, w2all + (size_t)e * OUTD * HID, eb2 + (size_t)e * OUTD,
                    gates + e, out, BSZ, OUTD, HID, HID, 0);
        }
    } else {
        f16* wbuf = (f16*)p;   p += SZ_WBUF;
        f16* hbuf = (f16*)p;
        f16* gh   = hbuf;

        transpose_f32_f16_kernel<<<dim3(HGD / 64, IND / 64, 1), 256, 0, stream>>>(
            gw1, wbuf, IND, HGD, IND, 0, 0);
        gemm256_kernel<true, false>
            <<<dim3((HGD / 256) * (BSZ / 256), 1, 1), 512, 0, stream>>>(
                x16, wbuf, gb1, nullptr, gh, BSZ, HGD, IND, HGD, 0);
        gate_softmax_kernel<<<BSZ / 4, 256, 0, stream>>>(gh, gw2, gb2, gates);

        for (int e = 0; e < NE; e++) {
            transpose_f32_f16_kernel<<<dim3(HID / 64, IND / 64, 1), 256, 0, stream>>>(
                ew1 + (size_t)e * IND * HID, wbuf, IND, HID, IND, 0, 0);
            gemm256_kernel<true, false>
                <<<dim3((HID / 256) * (BSZ / 256), 1, 1), 512, 0, stream>>>(
                    x16, wbuf, eb1 + (size_t)e * HID, nullptr, hbuf,
                    BSZ, HID, IND, HID, 0);

            transpose_f32_f16_kernel<<<dim3(OUTD / 64, HID / 64, 1), 256, 0, stream>>>(
                ew2 + (size_t)e * HID * OUTD, wbuf, HID, OUTD, HID, 0, 0);
            if (e == 0)
                gemmO_kernel<false, 0><<<(OUTD / 128) * (BSZ / 256), 512, 0, stream>>>(
                    hbuf, wbuf, eb2 + (size_t)e * OUTD, gates + e, out,
                    BSZ, OUTD, HID, HID, 0);
            else
                gemmO_kernel<true, 0><<<(OUTD / 128) * (BSZ / 256), 512, 0, stream>>>(
                    hbuf, wbuf, eb2 + (size_t)e * OUTD, gates + e, out,
                    BSZ, OUTD, HID, HID, 0);
        }
    }
}

// Round 13
// 1309.379 us; speedup vs baseline: 12.5496x; 1.0051x over previous
//
#include <hip/hip_runtime.h>

// ---------------------------------------------------------------------------
// MoE forward: gating MLP + 8 dense experts + gate-weighted combine.
// r13 = r12 (grouped G=4 fusion) + cross-barrier read/MFMA overlap:
// B halves both pre-read at P1/P5; A mh1 quadrant read moved to post-MFMA of
// the preceding phase (same registers, overwritten after last use). Breaks
// the strict LDS/MFMA alternation of lockstep phases. Stage calls and
// counted-vmcnt FIFO are UNCHANGED (ledger re-verified under new read times).
// ---------------------------------------------------------------------------

#define DI __device__ __forceinline__

typedef _Float16 f16;
typedef _Float16 f16x8 __attribute__((ext_vector_type(8)));
typedef float f32x4 __attribute__((ext_vector_type(4)));

constexpr int BSZ  = 8192;
constexpr int IND  = 1024;
constexpr int HID  = 4096;
constexpr int OUTD = 1024;
constexpr int NE   = 8;
constexpr int HGD  = 2048;

// ---------------- fp32 -> fp16 vectorized convert (8 elems/thread) ---------
__global__ __launch_bounds__(256) void conv_f32_f16_kernel(
    const float* __restrict__ in, f16* __restrict__ out)
{
    size_t i = ((size_t)blockIdx.x * 256 + threadIdx.x) * 8;
    const float4* p = (const float4*)(in + i);
    float4 a = p[0], b = p[1];
    f16x8 v = {(f16)a.x, (f16)a.y, (f16)a.z, (f16)a.w,
               (f16)b.x, (f16)b.y, (f16)b.z, (f16)b.w};
    *(f16x8*)(out + i) = v;
}

// transpose+convert: W[z][K][N] f32 -> Wt[z*zstride + n*ldo + z*kostep + k]
__global__ __launch_bounds__(256) void transpose_f32_f16_kernel(
    const float* __restrict__ W, f16* __restrict__ Wt, int K, int N,
    int ldo, size_t zstride, int kostep)
{
    const int z = blockIdx.z;
    W += (size_t)z * K * N;
    f16* base = Wt + (size_t)z * zstride + (size_t)z * kostep;
    __shared__ float t[64][65];
    int n0 = blockIdx.x * 64, k0 = blockIdx.y * 64;
    int tx = threadIdx.x & 63, ty = threadIdx.x >> 6;
#pragma unroll
    for (int i = 0; i < 16; i++) {
        int k = i * 4 + ty;
        t[k][tx] = W[(size_t)(k0 + k) * N + n0 + tx];
    }
    __syncthreads();
#pragma unroll
    for (int i = 0; i < 16; i++) {
        int n = i * 4 + ty;
        base[(size_t)(n0 + n) * ldo + k0 + tx] = (f16)t[tx][n];
    }
}

// ---------------- async global->LDS (16B per lane, wave-uniform dest) ------
DI void gload_lds16(const void* g, void* l)
{
    typedef const __attribute__((address_space(1))) unsigned int as1_t;
    typedef __attribute__((address_space(3))) unsigned int as3_t;
    __builtin_amdgcn_global_load_lds(
        (as1_t*)(unsigned long long)(__SIZE_TYPE__)g,
        (as3_t*)(unsigned int)(__SIZE_TYPE__)l,
        16, 0, 0);
}

// phase sync: head = bare barrier; tail = sched_barrier + barrier + clobber.
#define SYNC_HEAD    __builtin_amdgcn_s_barrier();
#define SYNC_TAIL                                                              \
    __builtin_amdgcn_sched_barrier(0);                                         \
    __builtin_amdgcn_s_barrier();                                              \
    asm volatile("" ::: "memory");

// ---------------------------------------------------------------------------
// gemm256: BM=256, BN=256, BK=64, 8 waves 2Mx4N. blockIdx.z = sub-expert.
// Read/MFMA overlap: P1 pre-reads A(mh0)+B(nh0)+B(nh1); A(mh1) read after
// P2's MFMA (consumed at P3); P3/P4 are wait-free MFMA phases.
// ---------------------------------------------------------------------------
template <bool RELU, bool GSCALE>
__global__ __launch_bounds__(512, 2) void gemm256_kernel(
    const f16* __restrict__ A, const f16* __restrict__ Bt,
    const float* __restrict__ bias, const float* __restrict__ gate,
    f16* __restrict__ Cptr, int M, int N, int K, int ldc, int e0)
{
    constexpr int BM = 256, BN = 256, BK = 64;
    constexpr int AT = BM * BK * 2, BT = BN * BK * 2;
    __shared__ __align__(16) f16 sA[2][BM * BK];
    __shared__ __align__(16) f16 sB[2][BN * BK];
    const char* sAc = (const char*)sA;
    const char* sBc = (const char*)sB;

    const int z = blockIdx.z;
    Bt   += (size_t)z * N * K;
    bias += (size_t)z * N;

    const int tid = threadIdx.x, wid = tid >> 6, lane = tid & 63;
    const int wm = wid >> 2, wn = wid & 3;
    const int nwg = gridDim.x, bid = blockIdx.x;
    const int wg = (bid & 7) * (nwg >> 3) + (bid >> 3);
    const int gx = N / BN;
    const size_t bm = (size_t)(wg / gx) * BM;
    const size_t bn = (size_t)(wg % gx) * BN;

    f32x4 acc[8][4] = {};

    const int rho  = tid >> 3;
    const int slot = (((tid & 7) << 4) ^ (((tid >> 3) & 7) << 4));
    const f16* pA = A  + (bm + rho) * (size_t)K + (slot >> 1);
    const f16* pB = Bt + (bn + rho) * (size_t)K + (slot >> 1);

    auto stA = [&](int b, int q, int T) {
        gload_lds16(pA + ((size_t)q * 64) * K + (size_t)T * BK,
                    (char*)sAc + b * AT + q * 8192 + wid * 1024);
    };
    auto stB = [&](int b, int q, int T) {
        gload_lds16(pB + ((size_t)q * 64) * K + (size_t)T * BK,
                    (char*)sBc + b * BT + q * 8192 + wid * 1024);
    };

    int offA0[8], offB0[4];
#pragma unroll
    for (int f = 0; f < 8; f++) {
        int r = wm * 128 + f * 16 + (lane & 15);
        offA0[f] = r * 128 + ((((lane >> 4) << 4)) ^ ((r & 7) << 4));
    }
#pragma unroll
    for (int f = 0; f < 4; f++) {
        int r = wn * 64 + f * 16 + (lane & 15);
        offB0[f] = r * 128 + ((((lane >> 4) << 4)) ^ ((r & 7) << 4));
    }

    f16x8 av[4][2], bv0[2][2], bv1[2][2];

#define LDAQ(B, MH)                                                            \
    _Pragma("unroll") for (int f = 0; f < 4; f++)                              \
    _Pragma("unroll") for (int kc = 0; kc < 2; kc++)                           \
        av[f][kc] = *(const f16x8*)(sAc + (B) * AT + (offA0[(MH)*4+f] ^ (kc << 6)));
#define LDBH(B, NH, BV)                                                        \
    _Pragma("unroll") for (int f = 0; f < 2; f++)                              \
    _Pragma("unroll") for (int kc = 0; kc < 2; kc++)                           \
        BV[f][kc] = *(const f16x8*)(sBc + (B) * BT + (offB0[(NH)*2+f] ^ (kc << 6)));
#define QUAD(MH, NH, BV)                                                       \
    __builtin_amdgcn_s_setprio(1);                                             \
    _Pragma("unroll") for (int f = 0; f < 4; f++)                              \
    _Pragma("unroll") for (int g = 0; g < 2; g++)                              \
    _Pragma("unroll") for (int kc = 0; kc < 2; kc++)                           \
        acc[(MH)*4+f][(NH)*2+g] = __builtin_amdgcn_mfma_f32_16x16x32_f16(      \
            av[f][kc], BV[g][kc], acc[(MH)*4+f][(NH)*2+g], 0, 0, 0);           \
    __builtin_amdgcn_s_setprio(0);

    const int NT = K / BK, NI = NT / 2;

    stA(0,0,0); stA(0,2,0); stB(0,0,0); stB(0,1,0); stB(0,2,0); stB(0,3,0);
    stA(0,1,0); stA(0,3,0);
    stA(1,0,1); stA(1,2,1); stB(1,0,1); stB(1,1,1); stB(1,2,1); stB(1,3,1);
    asm volatile("s_waitcnt vmcnt(6)");
    __builtin_amdgcn_s_barrier();
    asm volatile("" ::: "memory");

    for (int i = 0; i < NI - 1; ++i) {
        const int t = 2 * i;
        // ---- buf0 (tile t) ----
        LDAQ(0, 0) LDBH(0, 0, bv0) LDBH(0, 1, bv1)        // P1 pre-reads
        stA(1, 1, t + 1); stA(1, 3, t + 1);
        SYNC_HEAD
        QUAD(0, 0, bv0)
        SYNC_TAIL
        stA(0, 0, t + 2); stA(0, 2, t + 2);               // P2
        SYNC_HEAD
        QUAD(0, 1, bv1)
        LDAQ(0, 1)                                        // post-read mh1
        SYNC_TAIL
        stB(0, 0, t + 2); stB(0, 1, t + 2);               // P3
        SYNC_HEAD
        QUAD(1, 1, bv1)
        SYNC_TAIL
        stB(0, 2, t + 2); stB(0, 3, t + 2);               // P4
        SYNC_HEAD
        QUAD(1, 0, bv0)
        asm volatile("s_waitcnt vmcnt(6)");
        SYNC_TAIL
        // ---- buf1 (tile t+1) ----
        LDAQ(1, 0) LDBH(1, 0, bv0) LDBH(1, 1, bv1)        // P5 pre-reads
        stA(0, 1, t + 2); stA(0, 3, t + 2);
        SYNC_HEAD
        QUAD(0, 0, bv0)
        SYNC_TAIL
        stA(1, 0, t + 3); stA(1, 2, t + 3);               // P6
        SYNC_HEAD
        QUAD(0, 1, bv1)
        LDAQ(1, 1)                                        // post-read mh1
        SYNC_TAIL
        stB(1, 0, t + 3); stB(1, 1, t + 3);               // P7
        SYNC_HEAD
        QUAD(1, 1, bv1)
        SYNC_TAIL
        stB(1, 2, t + 3); stB(1, 3, t + 3);               // P8
        SYNC_HEAD
        QUAD(1, 0, bv0)
        asm volatile("s_waitcnt vmcnt(6)");
        SYNC_TAIL
    }
    {   // final iteration (tiles NT-2, NT-1)
        LDAQ(0, 0) LDBH(0, 0, bv0) LDBH(0, 1, bv1)
        stA(1, 1, NT - 1); stA(1, 3, NT - 1);
        SYNC_HEAD
        QUAD(0, 0, bv0)
        SYNC_TAIL
        SYNC_HEAD
        QUAD(0, 1, bv1)
        LDAQ(0, 1)
        SYNC_TAIL
        SYNC_HEAD
        QUAD(1, 1, bv1)
        SYNC_TAIL
        SYNC_HEAD
        QUAD(1, 0, bv0)
        asm volatile("s_waitcnt vmcnt(0)");
        SYNC_TAIL
        LDAQ(1, 0) LDBH(1, 0, bv0) LDBH(1, 1, bv1)
        SYNC_HEAD
        QUAD(0, 0, bv0)
        SYNC_TAIL
        SYNC_HEAD
        QUAD(0, 1, bv1)
        LDAQ(1, 1)
        SYNC_TAIL
        SYNC_HEAD
        QUAD(1, 1, bv1)
        SYNC_TAIL
        SYNC_HEAD
        QUAD(1, 0, bv0)
        SYNC_TAIL
    }
#undef LDAQ
#undef LDBH
#undef QUAD

    const size_t row0 = bm + (size_t)wm * 128;
    const int col0 = (int)bn + wn * 64;
    const int c0 = lane & 15, r0 = (lane >> 4) * 4;
    f16* Cz = Cptr + (size_t)z * N;
#pragma unroll
    for (int fm = 0; fm < 8; fm++)
#pragma unroll
        for (int r = 0; r < 4; r++) {
            const size_t row = row0 + fm * 16 + r0 + r;
            float g = 1.0f;
            if constexpr (GSCALE) g = gate[row * NE + e0 + z];
#pragma unroll
            for (int n = 0; n < 4; n++) {
                const size_t col = (size_t)col0 + n * 16 + c0;
                float v = acc[fm][n][r] + bias[col];
                if constexpr (RELU) v = fmaxf(v, 0.0f);
                if constexpr (GSCALE) v *= g;
                Cz[row * (size_t)ldc + col] = (f16)v;
            }
        }
}

// ---------------------------------------------------------------------------
// gemmO: BM=256, BN=128, BK=64, 8 waves 2Mx4N. B row stride = ldb.
// Read/MFMA overlap: P1 pre-reads A(mh0,kc0)+B(all); each later A-subtile
// read after the preceding phase's MFMA.
// ---------------------------------------------------------------------------
template <bool ACCUM, int GN>
__global__ __launch_bounds__(512, 2) void gemmO_kernel(
    const f16* __restrict__ A, const f16* __restrict__ Bt,
    const float* __restrict__ bias, const float* __restrict__ gate,
    float* __restrict__ Cptr, int M, int N, int K, int ldb, int e0)
{
    constexpr int BM = 256, BN = 128, BK = 64;
    constexpr int AT = BM * BK * 2, BT = BN * BK * 2;
    __shared__ __align__(16) f16 sA[2][BM * BK];
    __shared__ __align__(16) f16 sB[2][BN * BK];
    const char* sAc = (const char*)sA;
    const char* sBc = (const char*)sB;

    const int tid = threadIdx.x, wid = tid >> 6, lane = tid & 63;
    const int wm = wid >> 2, wn = wid & 3;
    const int nwg = gridDim.x, bid = blockIdx.x;
    const int wg = (bid & 7) * (nwg >> 3) + (bid >> 3);
    const int gx = N / BN;
    const size_t bm = (size_t)(wg / gx) * BM;
    const size_t bn = (size_t)(wg % gx) * BN;

    f32x4 acc[8][2] = {};

    const int rho  = tid >> 3;
    const int slot = (((tid & 7) << 4) ^ (((tid >> 3) & 7) << 4));
    const f16* pA = A  + (bm + rho) * (size_t)K   + (slot >> 1);
    const f16* pB = Bt + (bn + rho) * (size_t)ldb + (slot >> 1);

    auto stA = [&](int b, int q, int T) {
        gload_lds16(pA + ((size_t)q * 64) * K + (size_t)T * BK,
                    (char*)sAc + b * AT + q * 8192 + wid * 1024);
    };
    auto stB = [&](int b, int q, int T) {
        gload_lds16(pB + ((size_t)q * 64) * ldb + (size_t)T * BK,
                    (char*)sBc + b * BT + q * 8192 + wid * 1024);
    };

    int offA0[8], offB0[2];
#pragma unroll
    for (int f = 0; f < 8; f++) {
        int r = wm * 128 + f * 16 + (lane & 15);
        offA0[f] = r * 128 + ((((lane >> 4) << 4)) ^ ((r & 7) << 4));
    }
#pragma unroll
    for (int f = 0; f < 2; f++) {
        int r = wn * 32 + f * 16 + (lane & 15);
        offB0[f] = r * 128 + ((((lane >> 4) << 4)) ^ ((r & 7) << 4));
    }

    f16x8 av[4], bv[2][2];

#define LDA4(B, MH, KC)                                                        \
    _Pragma("unroll") for (int f = 0; f < 4; f++)                              \
        av[f] = *(const f16x8*)(sAc + (B) * AT + (offA0[(MH)*4+f] ^ ((KC) << 6)));
#define LDBA(B)                                                                \
    _Pragma("unroll") for (int f = 0; f < 2; f++)                              \
    _Pragma("unroll") for (int kc = 0; kc < 2; kc++)                           \
        bv[f][kc] = *(const f16x8*)(sBc + (B) * BT + (offB0[f] ^ (kc << 6)));
#define OCT(MH, KC)                                                            \
    __builtin_amdgcn_s_setprio(1);                                             \
    _Pragma("unroll") for (int f = 0; f < 4; f++)                              \
    _Pragma("unroll") for (int g = 0; g < 2; g++)                              \
        acc[(MH)*4+f][g] = __builtin_amdgcn_mfma_f32_16x16x32_f16(             \
            av[f], bv[g][KC], acc[(MH)*4+f][g], 0, 0, 0);                      \
    __builtin_amdgcn_s_setprio(0);

    const int NT = K / BK, NI = NT / 2;

    stA(0,0,0); stA(0,2,0); stB(0,0,0); stB(0,1,0); stA(0,1,0); stA(0,3,0);
    stA(1,0,1); stA(1,2,1); stB(1,0,1); stB(1,1,1);
    asm volatile("s_waitcnt vmcnt(4)");
    __builtin_amdgcn_s_barrier();
    asm volatile("" ::: "memory");

    for (int i = 0; i < NI - 1; ++i) {
        const int t = 2 * i;
        // ---- buf0 (tile t) ----
        LDA4(0, 0, 0) LDBA(0)
        stA(1, 1, t + 1); stA(1, 3, t + 1);
        SYNC_HEAD
        OCT(0, 0)
        LDA4(0, 0, 1)
        SYNC_TAIL
        SYNC_HEAD
        OCT(0, 1)
        LDA4(0, 1, 0)
        SYNC_TAIL
        stA(0, 0, t + 2); stA(0, 2, t + 2);
        SYNC_HEAD
        OCT(1, 0)
        LDA4(0, 1, 1)
        SYNC_TAIL
        stB(0, 0, t + 2); stB(0, 1, t + 2);
        SYNC_HEAD
        OCT(1, 1)
        asm volatile("s_waitcnt vmcnt(4)");
        SYNC_TAIL
        // ---- buf1 (tile t+1) ----
        LDA4(1, 0, 0) LDBA(1)
        stA(0, 1, t + 2); stA(0, 3, t + 2);
        SYNC_HEAD
        OCT(0, 0)
        LDA4(1, 0, 1)
        SYNC_TAIL
        SYNC_HEAD
        OCT(0, 1)
        LDA4(1, 1, 0)
        SYNC_TAIL
        stA(1, 0, t + 3); stA(1, 2, t + 3);
        SYNC_HEAD
        OCT(1, 0)
        LDA4(1, 1, 1)
        SYNC_TAIL
        stB(1, 0, t + 3); stB(1, 1, t + 3);
        SYNC_HEAD
        OCT(1, 1)
        asm volatile("s_waitcnt vmcnt(4)");
        SYNC_TAIL
    }
    {   // final iteration
        LDA4(0, 0, 0) LDBA(0)
        stA(1, 1, NT - 1); stA(1, 3, NT - 1);
        SYNC_HEAD
        OCT(0, 0)
        LDA4(0, 0, 1)
        SYNC_TAIL
        SYNC_HEAD
        OCT(0, 1)
        LDA4(0, 1, 0)
        SYNC_TAIL
        SYNC_HEAD
        OCT(1, 0)
        LDA4(0, 1, 1)
        SYNC_TAIL
        SYNC_HEAD
        OCT(1, 1)
        asm volatile("s_waitcnt vmcnt(0)");
        SYNC_TAIL
        LDA4(1, 0, 0) LDBA(1)
        SYNC_HEAD
        OCT(0, 0)
        LDA4(1, 0, 1)
        SYNC_TAIL
        SYNC_HEAD
        OCT(0, 1)
        LDA4(1, 1, 0)
        SYNC_TAIL
        SYNC_HEAD
        OCT(1, 0)
        LDA4(1, 1, 1)
        SYNC_TAIL
        SYNC_HEAD
        OCT(1, 1)
        SYNC_TAIL
    }
#undef LDA4
#undef LDBA
#undef OCT

    const size_t row0 = bm + (size_t)wm * 128;
    const int col0 = (int)bn + wn * 32;
    const int c0 = lane & 15, r0 = (lane >> 4) * 4;
#pragma unroll
    for (int fm = 0; fm < 8; fm++)
#pragma unroll
        for (int r = 0; r < 4; r++) {
            const size_t row = row0 + fm * 16 + r0 + r;
            if constexpr (GN == 0) {
                const float g = gate[row * NE];
#pragma unroll
                for (int n = 0; n < 2; n++) {
                    const size_t col = (size_t)col0 + n * 16 + c0;
                    float v = (acc[fm][n][r] + bias[col]) * g;
                    float* p = Cptr + row * (size_t)N + col;
                    *p = ACCUM ? (*p + v) : v;
                }
            } else {
                float gv[GN];
#pragma unroll
                for (int j = 0; j < GN; j++) gv[j] = gate[row * NE + e0 + j];
#pragma unroll
                for (int n = 0; n < 2; n++) {
                    const size_t col = (size_t)col0 + n * 16 + c0;
                    float bb = 0.f;
#pragma unroll
                    for (int j = 0; j < GN; j++)
                        bb = fmaf(gv[j], bias[(size_t)(e0 + j) * N + col], bb);
                    float v = acc[fm][n][r] + bb;
                    float* p = Cptr + row * (size_t)N + col;
                    *p = ACCUM ? (*p + v) : v;
                }
            }
        }
}

// --------- gating head: logits = gh@gw2 + gb2, softmax -> gates fp32 -------
__global__ __launch_bounds__(256) void gate_softmax_kernel(
    const f16* __restrict__ gh, const float* __restrict__ gw2,
    const float* __restrict__ gb2, float* __restrict__ gates)
{
    const int row  = blockIdx.x * 4 + (threadIdx.x >> 6);
    const int lane = threadIdx.x & 63;
    const f16* r = gh + (size_t)row * HGD;
    float acc[NE] = {};
    for (int kb = lane * 8; kb < HGD; kb += 512) {
        f16x8 v = *(const f16x8*)(r + kb);
#pragma unroll
        for (int j = 0; j < 8; j++) {
            float h = (float)v[j];
            const float* w = gw2 + (size_t)(kb + j) * NE;
#pragma unroll
            for (int e = 0; e < NE; e++) acc[e] = fmaf(h, w[e], acc[e]);
        }
    }
#pragma unroll
    for (int off = 32; off > 0; off >>= 1)
#pragma unroll
        for (int e = 0; e < NE; e++) acc[e] += __shfl_down(acc[e], off, 64);
    if (lane == 0) {
        float l[NE], m = -1e30f;
#pragma unroll
        for (int e = 0; e < NE; e++) { l[e] = acc[e] + gb2[e]; m = fmaxf(m, l[e]); }
        float s = 0.f;
#pragma unroll
        for (int e = 0; e < NE; e++) { l[e] = expf(l[e] - m); s += l[e]; }
        float inv = 1.0f / s;
#pragma unroll
        for (int e = 0; e < NE; e++) gates[(size_t)row * NE + e] = l[e] * inv;
    }
}

// ---------------------------------------------------------------------------
extern "C" void kernel_launch(void* const* d_in, const int* in_sizes, int n_in,
                              void* d_out, int out_size, void* d_ws, size_t ws_size,
                              hipStream_t stream)
{
    const float* x   = (const float*)d_in[0];
    const float* gw1 = (const float*)d_in[1];
    const float* gb1 = (const float*)d_in[2];
    const float* gw2 = (const float*)d_in[3];
    const float* gb2 = (const float*)d_in[4];
    const float* ew1 = (const float*)d_in[5];
    const float* eb1 = (const float*)d_in[6];
    const float* ew2 = (const float*)d_in[7];
    const float* eb2 = (const float*)d_in[8];
    float* out = (float*)d_out;

    const size_t SZ_GATES = 256 << 10;
    const size_t SZ_X16   = (size_t)BSZ * IND * 2;
    const size_t SZ_WBUF  = (size_t)HID * IND * 2;
    const size_t SZ_W1ALL = (size_t)NE * HID * IND * 2;
    const size_t SZ_W2ALL = (size_t)NE * OUTD * HID * 2;
    const size_t SZ_HB1   = (size_t)BSZ * HID * 2;
    const size_t BASE     = SZ_GATES + SZ_X16 + SZ_W1ALL + SZ_W2ALL;
    const size_t NEED_G4  = BASE + 4 * SZ_HB1;
    const size_t NEED_G2  = BASE + 2 * SZ_HB1;
    const size_t NEED_G1  = BASE + 1 * SZ_HB1;

    char* p = (char*)d_ws;
    float* gates = (float*)p;  p += SZ_GATES;
    f16* x16 = (f16*)p;        p += SZ_X16;

    conv_f32_f16_kernel<<<(BSZ * IND) / (256 * 8), 256, 0, stream>>>(x, x16);

    if (ws_size >= NEED_G2) {
        const int G = (ws_size >= NEED_G4) ? 4 : 2;
        f16* w1all = (f16*)p;  p += SZ_W1ALL;
        f16* w2cat = (f16*)p;  p += SZ_W2ALL;
        f16* hbufG = (f16*)p;
        f16* gh    = hbufG;

        transpose_f32_f16_kernel<<<dim3(HGD / 64, IND / 64, 1), 256, 0, stream>>>(
            gw1, w1all, IND, HGD, IND, 0, 0);
        gemm256_kernel<true, false>
            <<<dim3((HGD / 256) * (BSZ / 256), 1, 1), 512, 0, stream>>>(
                x16, w1all, gb1, nullptr, gh, BSZ, HGD, IND, HGD, 0);
        gate_softmax_kernel<<<BSZ / 4, 256, 0, stream>>>(gh, gw2, gb2, gates);

        transpose_f32_f16_kernel<<<dim3(HID / 64, IND / 64, NE), 256, 0, stream>>>(
            ew1, w1all, IND, HID, IND, (size_t)HID * IND, 0);
        transpose_f32_f16_kernel<<<dim3(OUTD / 64, HID / 64, NE), 256, 0, stream>>>(
            ew2, w2cat, HID, OUTD, NE * HID, 0, HID);

        for (int g = 0; g < NE / G; g++) {
            gemm256_kernel<true, true>
                <<<dim3((HID / 256) * (BSZ / 256), 1, G), 512, 0, stream>>>(
                    x16, w1all + (size_t)g * G * HID * IND, eb1 + g * G * HID,
                    gates, hbufG, BSZ, HID, IND, G * HID, g * G);
            if (G == 4) {
                if (g == 0)
                    gemmO_kernel<false, 4>
                        <<<(OUTD / 128) * (BSZ / 256), 512, 0, stream>>>(
                            hbufG, w2cat + (size_t)g * G * HID, eb2, gates, out,
                            BSZ, OUTD, G * HID, NE * HID, g * G);
                else
                    gemmO_kernel<true, 4>
                        <<<(OUTD / 128) * (BSZ / 256), 512, 0, stream>>>(
                            hbufG, w2cat + (size_t)g * G * HID, eb2, gates, out,
                            BSZ, OUTD, G * HID, NE * HID, g * G);
            } else {
                if (g == 0)
                    gemmO_kernel<false, 2>
                        <<<(OUTD / 128) * (BSZ / 256), 512, 0, stream>>>(
                            hbufG, w2cat + (size_t)g * G * HID, eb2, gates, out,
                            BSZ, OUTD, G * HID, NE * HID, g * G);
                else
                    gemmO_kernel<true, 2>
                        <<<(OUTD / 128) * (BSZ / 256), 512, 0, stream>>>(
                            hbufG, w2cat + (size_t)g * G * HID, eb2, gates, out,
                            BSZ, OUTD, G * HID, NE * HID, g * G);
            }
        }
    } else if (ws_size >= NEED_G1) {
        f16* w1all = (f16*)p;  p += SZ_W1ALL;
        f16* w2all = (f16*)p;  p += SZ_W2ALL;
        f16* hbuf  = (f16*)p;
        f16* gh    = hbuf;

        transpose_f32_f16_kernel<<<dim3(HGD / 64, IND / 64, 1), 256, 0, stream>>>(
            gw1, w1all, IND, HGD, IND, 0, 0);
        gemm256_kernel<true, false>
            <<<dim3((HGD / 256) * (BSZ / 256), 1, 1), 512, 0, stream>>>(
                x16, w1all, gb1, nullptr, gh, BSZ, HGD, IND, HGD, 0);
        gate_softmax_kernel<<<BSZ / 4, 256, 0, stream>>>(gh, gw2, gb2, gates);

        transpose_f32_f16_kernel<<<dim3(HID / 64, IND / 64, NE), 256, 0, stream>>>(
            ew1, w1all, IND, HID, IND, (size_t)HID * IND, 0);
        transpose_f32_f16_kernel<<<dim3(OUTD / 64, HID / 64, NE), 256, 0, stream>>>(
            ew2, w2all, HID, OUTD, HID, (size_t)OUTD * HID, 0);

        for (int e = 0; e < NE; e++) {
            gemm256_kernel<true, false>
                <<<dim3((HID / 256) * (BSZ / 256), 1, 1), 512, 0, stream>>>(
                    x16, w1all + (size_t)e * HID * IND, eb1 + (size_t)e * HID,
                    nullptr, hbuf, BSZ, HID, IND, HID, 0);
            if (e == 0)
                gemmO_kernel<false, 0><<<(OUTD / 128) * (BSZ / 256), 512, 0, stream>>>(
                    hbuf, w2all + (size_t)e * OUTD * HID, eb2 + (size_t)e * OUTD,
                    gates + e, out, BSZ, OUTD, HID, HID, 0);
            else
                gemmO_kernel<true, 0><<<(OUTD / 128) * (BSZ / 256), 512, 0, stream>>>(
                    hbuf, w2all + (size_t)e * OUTD * HID, eb2 + (size_t)e * OUTD,
                    gates + e, out, BSZ, OUTD, HID, HID, 0);
        }
    } else {
        f16* wbuf = (f16*)p;   p += SZ_WBUF;
        f16* hbuf = (f16*)p;
        f16* gh   = hbuf;

        transpose_f32_f16_kernel<<<dim3(HGD / 64, IND / 64, 1), 256, 0, stream>>>(
            gw1, wbuf, IND, HGD, IND, 0, 0);
        gemm256_kernel<true, false>
            <<<dim3((HGD / 256) * (BSZ / 256), 1, 1), 512, 0, stream>>>(
                x16, wbuf, gb1, nullptr, gh, BSZ, HGD, IND, HGD, 0);
        gate_softmax_kernel<<<BSZ / 4, 256, 0, stream>>>(gh, gw2, gb2, gates);

        for (int e = 0; e < NE; e++) {
            transpose_f32_f16_kernel<<<dim3(HID / 64, IND / 64, 1), 256, 0, stream>>>(
                ew1 + (size_t)e * IND * HID, wbuf, IND, HID, IND, 0, 0);
            gemm256_kernel<true, false>
                <<<dim3((HID / 256) * (BSZ / 256), 1, 1), 512, 0, stream>>>(
                    x16, wbuf, eb1 + (size_t)e * HID, nullptr, hbuf,
                    BSZ, HID, IND, HID, 0);

            transpose_f32_f16_kernel<<<dim3(OUTD / 64, HID / 64, 1), 256, 0, stream>>>(
                ew2 + (size_t)e * HID * OUTD, wbuf, HID, OUTD, HID, 0, 0);
            if (e == 0)
                gemmO_kernel<false, 0><<<(OUTD / 128) * (BSZ / 256), 512, 0, stream>>>(
                    hbuf, wbuf, eb2 + (size_t)e * OUTD, gates + e, out,
                    BSZ, OUTD, HID, HID, 0);
            else
                gemmO_kernel<true, 0><<<(OUTD / 128) * (BSZ / 256), 512, 0, stream>>>(
                    hbuf, wbuf, eb2 + (size_t)e * OUTD, gates + e, out,
                    BSZ, OUTD, HID, HID, 0);
        }
    }
}